// Round 3
// baseline (1082.124 us; speedup 1.0000x reference)
//
#include <hip/hip_runtime.h>
#include <cstdint>
#include <cstddef>

#define L_ 256
#define C_ 128
#define H_ 4
#define D_ 32
#define NP_ (L_ * L_)

typedef unsigned short u16;
typedef uint32_t u32;

__device__ __forceinline__ float bflo(u32 u) { union { u32 i; float f; } v; v.i = u << 16; return v.f; }
__device__ __forceinline__ float bfhi(u32 u) { union { u32 i; float f; } v; v.i = u & 0xffff0000u; return v.f; }
__device__ __forceinline__ u16 f2b(float f) {
    u32 x = __float_as_uint(f);
    return (u16)((x + 0x7fffu + ((x >> 16) & 1u)) >> 16);
}
__device__ __forceinline__ u32 pk2(float lo, float hi) {
    return ((u32)f2b(hi) << 16) | (u32)f2b(lo);
}
__device__ __forceinline__ void unpack8(uint4 w, float* f) {
    f[0] = bflo(w.x); f[1] = bfhi(w.x); f[2] = bflo(w.y); f[3] = bfhi(w.y);
    f[4] = bflo(w.z); f[5] = bfhi(w.z); f[6] = bflo(w.w); f[7] = bfhi(w.w);
}

// ---------------------------------------------------------------------------
// Kernel 1: LayerNorm + Q/K/V projections (bf16 ws stores) + bias projection
// (fp32, transposed). block = 128 threads, 8 positions; grid = 8192.
// All global inputs are FP32 (per the reference).
// ---------------------------------------------------------------------------
__global__ __launch_bounds__(128) void k_ln_qkv(
    const float* __restrict__ pair, const float* __restrict__ ln_g, const float* __restrict__ ln_b,
    const float* __restrict__ Wq, const float* __restrict__ Wk, const float* __restrict__ Wv,
    const float* __restrict__ Wbias,
    u16* __restrict__ qo, u16* __restrict__ ko, u16* __restrict__ vo,
    float* __restrict__ biasT)
{
    __shared__ float zsh[8][C_];
    __shared__ float red[2][4];    // double-buffered by iteration parity (race fix)
    const int t = threadIdx.x;
    const int p0 = blockIdx.x * 8;
    const float g  = ln_g[t];
    const float bb = ln_b[t];

    float xs[8];
    #pragma unroll
    for (int r = 0; r < 8; ++r) xs[r] = pair[(size_t)(p0 + r) * C_ + t];

    #pragma unroll
    for (int r = 0; r < 8; ++r) {
        float x = xs[r];
        float s = x, sq = x * x;
        #pragma unroll
        for (int off = 32; off; off >>= 1) {
            s  += __shfl_down(s, off);
            sq += __shfl_down(sq, off);
        }
        if ((t & 63) == 0) { red[r & 1][t >> 6] = s; red[r & 1][2 + (t >> 6)] = sq; }
        __syncthreads();
        float mu  = (red[r & 1][0] + red[r & 1][1]) * (1.0f / C_);
        float var = (red[r & 1][2] + red[r & 1][3]) * (1.0f / C_) - mu * mu;
        zsh[r][t] = (x - mu) * rsqrtf(fmaxf(var, 0.f) + 1e-5f) * g + bb;
    }
    __syncthreads();

    // Each thread computes column t of Q, K, V for the 8 staged positions.
    float aq[8], ak[8], av[8];
    #pragma unroll
    for (int r = 0; r < 8; ++r) { aq[r] = 0.f; ak[r] = 0.f; av[r] = 0.f; }

    for (int c = 0; c < C_; c += 4) {
        float wq[4], wk[4], wv[4];
        #pragma unroll
        for (int u = 0; u < 4; ++u) {
            wq[u] = Wq[(size_t)(c + u) * C_ + t];
            wk[u] = Wk[(size_t)(c + u) * C_ + t];
            wv[u] = Wv[(size_t)(c + u) * C_ + t];
        }
        #pragma unroll
        for (int r = 0; r < 8; ++r) {
            float4 z4 = *(const float4*)&zsh[r][c];
            aq[r] += z4.x * wq[0] + z4.y * wq[1] + z4.z * wq[2] + z4.w * wq[3];
            ak[r] += z4.x * wk[0] + z4.y * wk[1] + z4.z * wk[2] + z4.w * wk[3];
            av[r] += z4.x * wv[0] + z4.y * wv[1] + z4.z * wv[2] + z4.w * wv[3];
        }
    }
    #pragma unroll
    for (int r = 0; r < 8; ++r) {
        size_t o = (size_t)(p0 + r) * C_ + t;
        qo[o] = f2b(aq[r]); ko[o] = f2b(ak[r]); vo[o] = f2b(av[r]);
    }

    // bias projection: 32 tasks (8 pos x 4 heads); store transposed biasT[h][k][j]
    if (t < 32) {
        int pos = t >> 2, h = t & 3;
        float a = 0.f;
        for (int c = 0; c < C_; ++c) a += zsh[pos][c] * Wbias[c * H_ + h];
        int p = p0 + pos;              // p = j*256 + k
        biasT[h * NP_ + (p & 255) * 256 + (p >> 8)] = a;
    }
}

// ---------------------------------------------------------------------------
// Kernel 2: attention per (i, h). block = 128 threads, each owns rows j=t, t+128
// grid = 1024. K/V staged in LDS as packed bf16; softmax w/o max-sub (logits
// bounded ~|3|). qa is BOTH q input and ao output (in-place): block (i,h)'s q
// region is read only by the threads that later write the same elements; reads
// strictly precede writes in-thread; regions disjoint across blocks.
// ---------------------------------------------------------------------------
__global__ __launch_bounds__(128) void k_attn(
    u16* __restrict__ qa, const u16* __restrict__ ki, const u16* __restrict__ vi,
    const float* __restrict__ biasT)
{
    __shared__ uint4 Ksh[L_ * 4];   // 256 rows x 32 bf16 = 16 KB
    __shared__ uint4 Vsh[L_ * 4];
    const int t = threadIdx.x;
    const int i = blockIdx.x >> 2;
    const int h = blockIdx.x & 3;

    for (int r = t; r < L_; r += 128) {
        const uint4* sk = (const uint4*)(ki + (size_t)(i * L_ + r) * C_ + h * D_);
        const uint4* sv = (const uint4*)(vi + (size_t)(i * L_ + r) * C_ + h * D_);
        #pragma unroll
        for (int u = 0; u < 4; ++u) { Ksh[r * 4 + u] = sk[u]; Vsh[r * 4 + u] = sv[u]; }
    }

    const float scale = 0.17677669529663687f;  // 1/sqrt(32)
    float q0[D_], q1[D_];
    {
        const uint4* s0 = (const uint4*)(qa + (size_t)(i * L_ + t) * C_ + h * D_);
        const uint4* s1 = (const uint4*)(qa + (size_t)(i * L_ + t + 128) * C_ + h * D_);
        #pragma unroll
        for (int u = 0; u < 4; ++u) {
            float f[8];
            unpack8(s0[u], f);
            #pragma unroll
            for (int d = 0; d < 8; ++d) q0[u * 8 + d] = f[d] * scale;
            unpack8(s1[u], f);
            #pragma unroll
            for (int d = 0; d < 8; ++d) q1[u * 8 + d] = f[d] * scale;
        }
    }
    __syncthreads();

    float acc0[D_], acc1[D_];
    #pragma unroll
    for (int d = 0; d < D_; ++d) { acc0[d] = 0.f; acc1[d] = 0.f; }
    float l0 = 0.f, l1 = 0.f;
    const float* bT = biasT + h * NP_;

    float b0n = bT[t], b1n = bT[t + 128];   // one-iteration bias lookahead
    for (int kk = 0; kk < L_; ++kk) {
        float b0 = b0n, b1 = b1n;
        if (kk < L_ - 1) {
            b0n = bT[(kk + 1) * 256 + t];
            b1n = bT[(kk + 1) * 256 + t + 128];
        }
        float s0 = 0.f, s1 = 0.f;
        #pragma unroll
        for (int u = 0; u < 4; ++u) {
            float f[8]; unpack8(Ksh[kk * 4 + u], f);
            #pragma unroll
            for (int d = 0; d < 8; ++d) { s0 += f[d] * q0[u * 8 + d]; s1 += f[d] * q1[u * 8 + d]; }
        }
        float e0 = __expf(s0 + b0);
        float e1 = __expf(s1 + b1);
        l0 += e0; l1 += e1;
        #pragma unroll
        for (int u = 0; u < 4; ++u) {
            float f[8]; unpack8(Vsh[kk * 4 + u], f);
            #pragma unroll
            for (int d = 0; d < 8; ++d) { acc0[u * 8 + d] += e0 * f[d]; acc1[u * 8 + d] += e1 * f[d]; }
        }
    }

    float n0 = 1.f / l0, n1 = 1.f / l1;
    u32 pk[16];
    #pragma unroll
    for (int d = 0; d < 16; ++d) pk[d] = pk2(acc0[2 * d] * n0, acc0[2 * d + 1] * n0);
    uint4* dst0 = (uint4*)(qa + (size_t)(i * L_ + t) * C_ + h * D_);
    #pragma unroll
    for (int u = 0; u < 4; ++u) dst0[u] = make_uint4(pk[u * 4], pk[u * 4 + 1], pk[u * 4 + 2], pk[u * 4 + 3]);
    #pragma unroll
    for (int d = 0; d < 16; ++d) pk[d] = pk2(acc1[2 * d] * n1, acc1[2 * d + 1] * n1);
    uint4* dst1 = (uint4*)(qa + (size_t)(i * L_ + t + 128) * C_ + h * D_);
    #pragma unroll
    for (int u = 0; u < 4; ++u) dst1[u] = make_uint4(pk[u * 4], pk[u * 4 + 1], pk[u * 4 + 2], pk[u * 4 + 3]);
}

// ---------------------------------------------------------------------------
// Kernel 3: out = pair + sigmoid(pair@Wg + bg) * (ao@Wo + bo)   (all fp32 I/O,
// ao is bf16 ws). thread-per-position; block = 256 pos x 64 cols (split by
// blockIdx parity so W addresses stay wave-uniform). grid = 512.
// ---------------------------------------------------------------------------
__global__ __launch_bounds__(256) void k_out(
    const u16* __restrict__ ao, const float* __restrict__ pair,
    const float* __restrict__ Wo, const float* __restrict__ bo,
    const float* __restrict__ Wg, const float* __restrict__ bg,
    float* __restrict__ out)
{
    const int t = threadIdx.x;
    const int p = (blockIdx.x >> 1) * 256 + t;
    const int colBase = (blockIdx.x & 1) * 64;
    const u16*  aoRow = ao   + (size_t)p * C_;
    const float* prRow = pair + (size_t)p * C_;

    for (int ct = 0; ct < 64; ct += 8) {
        const int col0 = colBase + ct;
        float acco[8], accg[8];
        #pragma unroll
        for (int u = 0; u < 8; ++u) { acco[u] = 0.f; accg[u] = 0.f; }

        for (int c = 0; c < C_; c += 4) {
            uint2  arow = *(const uint2*)(aoRow + c);       // 4 bf16
            float4 prow = *(const float4*)(prRow + c);      // 4 fp32
            float av[4] = { bflo(arow.x), bfhi(arow.x), bflo(arow.y), bfhi(arow.y) };
            float pv[4] = { prow.x, prow.y, prow.z, prow.w };
            #pragma unroll
            for (int cc = 0; cc < 4; ++cc) {
                const float* woRow = Wo + (size_t)(c + cc) * C_ + col0;  // wave-uniform
                const float* wgRow = Wg + (size_t)(c + cc) * C_ + col0;  // wave-uniform
                float4 wo0 = *(const float4*)(woRow);
                float4 wo1 = *(const float4*)(woRow + 4);
                float4 wg0 = *(const float4*)(wgRow);
                float4 wg1 = *(const float4*)(wgRow + 4);
                const float* wof = (const float*)&wo0;
                const float* wgf = (const float*)&wg0;
                #pragma unroll
                for (int u = 0; u < 4; ++u) { acco[u] += av[cc] * wof[u]; accg[u] += pv[cc] * wgf[u]; }
                wof = (const float*)&wo1; wgf = (const float*)&wg1;
                #pragma unroll
                for (int u = 0; u < 4; ++u) { acco[4 + u] += av[cc] * wof[u]; accg[4 + u] += pv[cc] * wgf[u]; }
            }
        }

        float res[8];
        #pragma unroll
        for (int u = 0; u < 8; ++u) {
            float o  = acco[u] + bo[col0 + u];
            float gg = accg[u] + bg[col0 + u];
            float sg = 1.f / (1.f + __expf(-gg));
            res[u] = prRow[col0 + u] + sg * o;
        }
        *(float4*)(out + (size_t)p * C_ + col0)     = make_float4(res[0], res[1], res[2], res[3]);
        *(float4*)(out + (size_t)p * C_ + col0 + 4) = make_float4(res[4], res[5], res[6], res[7]);
    }
}

// ---------------------------------------------------------------------------
// Workspace layout (49 MB):
//   [0,  1 MB)  biasT  fp32 [H][k][j]
//   [1, 17 MB)  qa     bf16  (q, overwritten in-place with ao by k_attn)
//   [17,33 MB)  k      bf16
//   [33,49 MB)  v      bf16
// ---------------------------------------------------------------------------
extern "C" void kernel_launch(void* const* d_in, const int* in_sizes, int n_in,
                              void* d_out, int out_size, void* d_ws, size_t ws_size,
                              hipStream_t stream) {
    const float* pair  = (const float*)d_in[0];
    const float* ln_g  = (const float*)d_in[1];
    const float* ln_b  = (const float*)d_in[2];
    const float* Wq    = (const float*)d_in[3];
    const float* Wk    = (const float*)d_in[4];
    const float* Wv    = (const float*)d_in[5];
    const float* Wbias = (const float*)d_in[6];
    const float* Wo    = (const float*)d_in[7];
    const float* bo    = (const float*)d_in[8];
    const float* Wg    = (const float*)d_in[9];
    const float* bg    = (const float*)d_in[10];
    float* out = (float*)d_out;

    float* biasT = (float*)d_ws;                      // 1 MB fp32, [H][k][j]
    u16* qa = (u16*)(biasT + (size_t)H_ * NP_);       // 16 MB (q -> ao in place)
    u16* k  = qa + (size_t)NP_ * C_;                  // 16 MB
    u16* v  = k  + (size_t)NP_ * C_;                  // 16 MB

    k_ln_qkv<<<NP_ / 8, 128, 0, stream>>>(pair, ln_g, ln_b, Wq, Wk, Wv, Wbias, qa, k, v, biasT);
    k_attn<<<L_ * H_, 128, 0, stream>>>(qa, k, v, biasT);
    k_out<<<(NP_ / 256) * 2, 256, 0, stream>>>(qa, pair, Wo, bo, Wg, bg, out);
}

// Round 4
// 528.095 us; speedup vs baseline: 2.0491x; 2.0491x over previous
//
#include <hip/hip_runtime.h>
#include <cstdint>
#include <cstddef>

#define L_ 256
#define C_ 128
#define H_ 4
#define D_ 32
#define NP_ (L_ * L_)

typedef unsigned short u16;
typedef uint32_t u32;

__device__ __forceinline__ float bflo(u32 u) { union { u32 i; float f; } v; v.i = u << 16; return v.f; }
__device__ __forceinline__ float bfhi(u32 u) { union { u32 i; float f; } v; v.i = u & 0xffff0000u; return v.f; }
__device__ __forceinline__ u16 f2b(float f) {
    u32 x = __float_as_uint(f);
    return (u16)((x + 0x7fffu + ((x >> 16) & 1u)) >> 16);
}
__device__ __forceinline__ u32 pk2(float lo, float hi) {
    return ((u32)f2b(hi) << 16) | (u32)f2b(lo);
}
__device__ __forceinline__ void unpack8(uint4 w, float* f) {
    f[0] = bflo(w.x); f[1] = bfhi(w.x); f[2] = bflo(w.y); f[3] = bfhi(w.y);
    f[4] = bflo(w.z); f[5] = bfhi(w.z); f[6] = bflo(w.w); f[7] = bfhi(w.w);
}

// ---------------------------------------------------------------------------
// Kernel 1: LayerNorm + Q/K/V projections (bf16 ws stores) + bias projection
// (fp32, transposed). block = 128 threads, 8 positions; grid = 8192.  (unchanged)
// ---------------------------------------------------------------------------
__global__ __launch_bounds__(128) void k_ln_qkv(
    const float* __restrict__ pair, const float* __restrict__ ln_g, const float* __restrict__ ln_b,
    const float* __restrict__ Wq, const float* __restrict__ Wk, const float* __restrict__ Wv,
    const float* __restrict__ Wbias,
    u16* __restrict__ qo, u16* __restrict__ ko, u16* __restrict__ vo,
    float* __restrict__ biasT)
{
    __shared__ float zsh[8][C_];
    __shared__ float red[2][4];
    const int t = threadIdx.x;
    const int p0 = blockIdx.x * 8;
    const float g  = ln_g[t];
    const float bb = ln_b[t];

    float xs[8];
    #pragma unroll
    for (int r = 0; r < 8; ++r) xs[r] = pair[(size_t)(p0 + r) * C_ + t];

    #pragma unroll
    for (int r = 0; r < 8; ++r) {
        float x = xs[r];
        float s = x, sq = x * x;
        #pragma unroll
        for (int off = 32; off; off >>= 1) {
            s  += __shfl_down(s, off);
            sq += __shfl_down(sq, off);
        }
        if ((t & 63) == 0) { red[r & 1][t >> 6] = s; red[r & 1][2 + (t >> 6)] = sq; }
        __syncthreads();
        float mu  = (red[r & 1][0] + red[r & 1][1]) * (1.0f / C_);
        float var = (red[r & 1][2] + red[r & 1][3]) * (1.0f / C_) - mu * mu;
        zsh[r][t] = (x - mu) * rsqrtf(fmaxf(var, 0.f) + 1e-5f) * g + bb;
    }
    __syncthreads();

    float aq[8], ak[8], av[8];
    #pragma unroll
    for (int r = 0; r < 8; ++r) { aq[r] = 0.f; ak[r] = 0.f; av[r] = 0.f; }

    for (int c = 0; c < C_; c += 4) {
        float wq[4], wk[4], wv[4];
        #pragma unroll
        for (int u = 0; u < 4; ++u) {
            wq[u] = Wq[(size_t)(c + u) * C_ + t];
            wk[u] = Wk[(size_t)(c + u) * C_ + t];
            wv[u] = Wv[(size_t)(c + u) * C_ + t];
        }
        #pragma unroll
        for (int r = 0; r < 8; ++r) {
            float4 z4 = *(const float4*)&zsh[r][c];
            aq[r] += z4.x * wq[0] + z4.y * wq[1] + z4.z * wq[2] + z4.w * wq[3];
            ak[r] += z4.x * wk[0] + z4.y * wk[1] + z4.z * wk[2] + z4.w * wk[3];
            av[r] += z4.x * wv[0] + z4.y * wv[1] + z4.z * wv[2] + z4.w * wv[3];
        }
    }
    #pragma unroll
    for (int r = 0; r < 8; ++r) {
        size_t o = (size_t)(p0 + r) * C_ + t;
        qo[o] = f2b(aq[r]); ko[o] = f2b(ak[r]); vo[o] = f2b(av[r]);
    }

    if (t < 32) {
        int pos = t >> 2, h = t & 3;
        float a = 0.f;
        for (int c = 0; c < C_; ++c) a += zsh[pos][c] * Wbias[c * H_ + h];
        int p = p0 + pos;              // p = j*256 + k
        biasT[h * NP_ + (p & 255) * 256 + (p >> 8)] = a;
    }
}

// ---------------------------------------------------------------------------
// Kernel 2: attention per (i, h).  (unchanged)
// ---------------------------------------------------------------------------
__global__ __launch_bounds__(128) void k_attn(
    u16* __restrict__ qa, const u16* __restrict__ ki, const u16* __restrict__ vi,
    const float* __restrict__ biasT)
{
    __shared__ uint4 Ksh[L_ * 4];
    __shared__ uint4 Vsh[L_ * 4];
    const int t = threadIdx.x;
    const int i = blockIdx.x >> 2;
    const int h = blockIdx.x & 3;

    for (int r = t; r < L_; r += 128) {
        const uint4* sk = (const uint4*)(ki + (size_t)(i * L_ + r) * C_ + h * D_);
        const uint4* sv = (const uint4*)(vi + (size_t)(i * L_ + r) * C_ + h * D_);
        #pragma unroll
        for (int u = 0; u < 4; ++u) { Ksh[r * 4 + u] = sk[u]; Vsh[r * 4 + u] = sv[u]; }
    }

    const float scale = 0.17677669529663687f;
    float q0[D_], q1[D_];
    {
        const uint4* s0 = (const uint4*)(qa + (size_t)(i * L_ + t) * C_ + h * D_);
        const uint4* s1 = (const uint4*)(qa + (size_t)(i * L_ + t + 128) * C_ + h * D_);
        #pragma unroll
        for (int u = 0; u < 4; ++u) {
            float f[8];
            unpack8(s0[u], f);
            #pragma unroll
            for (int d = 0; d < 8; ++d) q0[u * 8 + d] = f[d] * scale;
            unpack8(s1[u], f);
            #pragma unroll
            for (int d = 0; d < 8; ++d) q1[u * 8 + d] = f[d] * scale;
        }
    }
    __syncthreads();

    float acc0[D_], acc1[D_];
    #pragma unroll
    for (int d = 0; d < D_; ++d) { acc0[d] = 0.f; acc1[d] = 0.f; }
    float l0 = 0.f, l1 = 0.f;
    const float* bT = biasT + h * NP_;

    float b0n = bT[t], b1n = bT[t + 128];
    for (int kk = 0; kk < L_; ++kk) {
        float b0 = b0n, b1 = b1n;
        if (kk < L_ - 1) {
            b0n = bT[(kk + 1) * 256 + t];
            b1n = bT[(kk + 1) * 256 + t + 128];
        }
        float s0 = 0.f, s1 = 0.f;
        #pragma unroll
        for (int u = 0; u < 4; ++u) {
            float f[8]; unpack8(Ksh[kk * 4 + u], f);
            #pragma unroll
            for (int d = 0; d < 8; ++d) { s0 += f[d] * q0[u * 8 + d]; s1 += f[d] * q1[u * 8 + d]; }
        }
        float e0 = __expf(s0 + b0);
        float e1 = __expf(s1 + b1);
        l0 += e0; l1 += e1;
        #pragma unroll
        for (int u = 0; u < 4; ++u) {
            float f[8]; unpack8(Vsh[kk * 4 + u], f);
            #pragma unroll
            for (int d = 0; d < 8; ++d) { acc0[u * 8 + d] += e0 * f[d]; acc1[u * 8 + d] += e1 * f[d]; }
        }
    }

    float n0 = 1.f / l0, n1 = 1.f / l1;
    u32 pk[16];
    #pragma unroll
    for (int d = 0; d < 16; ++d) pk[d] = pk2(acc0[2 * d] * n0, acc0[2 * d + 1] * n0);
    uint4* dst0 = (uint4*)(qa + (size_t)(i * L_ + t) * C_ + h * D_);
    #pragma unroll
    for (int u = 0; u < 4; ++u) dst0[u] = make_uint4(pk[u * 4], pk[u * 4 + 1], pk[u * 4 + 2], pk[u * 4 + 3]);
    #pragma unroll
    for (int d = 0; d < 16; ++d) pk[d] = pk2(acc1[2 * d] * n1, acc1[2 * d + 1] * n1);
    uint4* dst1 = (uint4*)(qa + (size_t)(i * L_ + t + 128) * C_ + h * D_);
    #pragma unroll
    for (int u = 0; u < 4; ++u) dst1[u] = make_uint4(pk[u * 4], pk[u * 4 + 1], pk[u * 4 + 2], pk[u * 4 + 3]);
}

// ---------------------------------------------------------------------------
// Kernel 3 (REWRITTEN): out = pair + sigmoid(pair@Wg + bg) * (ao@Wo + bo)
// Block = 512 threads, 64 positions; rows staged ONCE in LDS (pair fp32 padded
// [64][132], ao bf16 [64][136]) -> no row re-reads to HBM (was 16x). Wave w
// owns columns w*16..+15 (wave-uniform W addresses -> broadcast loads); lane l
// owns row l (LDS b128 reads, data-limited). 32 fp32 accums/thread.
// grid = 1024.
// ---------------------------------------------------------------------------
__global__ __launch_bounds__(512) void k_out(
    const u16* __restrict__ ao, const float* __restrict__ pair,
    const float* __restrict__ Wo, const float* __restrict__ bo,
    const float* __restrict__ Wg, const float* __restrict__ bg,
    float* __restrict__ out)
{
    __shared__ float zsh[64][132];   // raw pair rows, +4 pad (16B-aligned rows)
    __shared__ u16   ash[64][136];   // ao rows bf16, +8 pad (16B-aligned rows)

    const int t  = threadIdx.x;
    const int p0 = blockIdx.x * 64;

    // ---- stage 64 pair rows (2048 float4, coalesced) ----
    #pragma unroll
    for (int j = 0; j < 4; ++j) {
        int idx = t + j * 512;            // 0..2047
        int pos = idx >> 5;               // /32 float4 per row
        int c   = (idx & 31) * 4;
        *(float4*)&zsh[pos][c] = *(const float4*)(pair + (size_t)(p0 + pos) * C_ + c);
    }
    // ---- stage 64 ao rows (1024 uint4, coalesced) ----
    #pragma unroll
    for (int j = 0; j < 2; ++j) {
        int idx = t + j * 512;            // 0..1023
        int pos = idx >> 4;               // /16 uint4 per row
        int c   = (idx & 15) * 8;
        *(uint4*)&ash[pos][c] = *(const uint4*)(ao + (size_t)(p0 + pos) * C_ + c);
    }
    __syncthreads();

    const int l    = t & 63;                                      // row within tile
    const int col0 = __builtin_amdgcn_readfirstlane((t >> 6) * 16); // wave-uniform col group

    float accO[16], accG[16];
    #pragma unroll
    for (int u = 0; u < 16; ++u) { accO[u] = 0.f; accG[u] = 0.f; }

    for (int c4 = 0; c4 < C_; c4 += 4) {
        float4 z4 = *(const float4*)&zsh[l][c4];
        uint2  a2 = *(const uint2*)&ash[l][c4];
        float a4[4] = { bflo(a2.x), bfhi(a2.x), bflo(a2.y), bfhi(a2.y) };
        const float* zf = (const float*)&z4;
        #pragma unroll
        for (int cc = 0; cc < 4; ++cc) {
            const float* woP = Wo + (size_t)(c4 + cc) * C_ + col0;  // wave-uniform
            const float* wgP = Wg + (size_t)(c4 + cc) * C_ + col0;  // wave-uniform
            float aa = a4[cc], zz = zf[cc];
            #pragma unroll
            for (int u = 0; u < 4; ++u) {
                float4 wo = *(const float4*)(woP + u * 4);
                float4 wg = *(const float4*)(wgP + u * 4);
                accO[u * 4 + 0] += aa * wo.x;  accG[u * 4 + 0] += zz * wg.x;
                accO[u * 4 + 1] += aa * wo.y;  accG[u * 4 + 1] += zz * wg.y;
                accO[u * 4 + 2] += aa * wo.z;  accG[u * 4 + 2] += zz * wg.z;
                accO[u * 4 + 3] += aa * wo.w;  accG[u * 4 + 3] += zz * wg.w;
            }
        }
    }

    // ---- epilogue: residual pair comes from LDS; biases wave-uniform ----
    float* dst = out + (size_t)(p0 + l) * C_ + col0;
    #pragma unroll
    for (int u = 0; u < 4; ++u) {
        float4 bo4 = *(const float4*)(bo + col0 + u * 4);
        float4 bg4 = *(const float4*)(bg + col0 + u * 4);
        float4 pz  = *(const float4*)&zsh[l][col0 + u * 4];
        float4 r;
        float o0 = accO[u*4+0] + bo4.x, g0 = accG[u*4+0] + bg4.x;
        float o1 = accO[u*4+1] + bo4.y, g1 = accG[u*4+1] + bg4.y;
        float o2 = accO[u*4+2] + bo4.z, g2 = accG[u*4+2] + bg4.z;
        float o3 = accO[u*4+3] + bo4.w, g3 = accG[u*4+3] + bg4.w;
        r.x = pz.x + o0 / (1.f + __expf(-g0)) * 1.f * (1.f) * (1.f) * (1.f) * (1.f) * (1.f) * (1.f) * (1.f) * (1.f) * (1.f);
        r.x = pz.x + (1.f / (1.f + __expf(-g0))) * o0;
        r.y = pz.y + (1.f / (1.f + __expf(-g1))) * o1;
        r.z = pz.z + (1.f / (1.f + __expf(-g2))) * o2;
        r.w = pz.w + (1.f / (1.f + __expf(-g3))) * o3;
        *(float4*)(dst + u * 4) = r;
    }
}

// ---------------------------------------------------------------------------
// Workspace layout (49 MB):
//   [0,  1 MB)  biasT  fp32 [H][k][j]
//   [1, 17 MB)  qa     bf16  (q, overwritten in-place with ao by k_attn)
//   [17,33 MB)  k      bf16
//   [33,49 MB)  v      bf16
// ---------------------------------------------------------------------------
extern "C" void kernel_launch(void* const* d_in, const int* in_sizes, int n_in,
                              void* d_out, int out_size, void* d_ws, size_t ws_size,
                              hipStream_t stream) {
    const float* pair  = (const float*)d_in[0];
    const float* ln_g  = (const float*)d_in[1];
    const float* ln_b  = (const float*)d_in[2];
    const float* Wq    = (const float*)d_in[3];
    const float* Wk    = (const float*)d_in[4];
    const float* Wv    = (const float*)d_in[5];
    const float* Wbias = (const float*)d_in[6];
    const float* Wo    = (const float*)d_in[7];
    const float* bo    = (const float*)d_in[8];
    const float* Wg    = (const float*)d_in[9];
    const float* bg    = (const float*)d_in[10];
    float* out = (float*)d_out;

    float* biasT = (float*)d_ws;
    u16* qa = (u16*)(biasT + (size_t)H_ * NP_);
    u16* k  = qa + (size_t)NP_ * C_;
    u16* v  = k  + (size_t)NP_ * C_;

    k_ln_qkv<<<NP_ / 8, 128, 0, stream>>>(pair, ln_g, ln_b, Wq, Wk, Wv, Wbias, qa, k, v, biasT);
    k_attn<<<L_ * H_, 128, 0, stream>>>(qa, k, v, biasT);
    k_out<<<NP_ / 64, 512, 0, stream>>>(qa, pair, Wo, bo, Wg, bg, out);
}

// Round 5
// 344.514 us; speedup vs baseline: 3.1410x; 1.5329x over previous
//
#include <hip/hip_runtime.h>
#include <cstdint>
#include <cstddef>

#define L_ 256
#define C_ 128
#define H_ 4
#define D_ 32
#define NP_ (L_ * L_)

typedef unsigned short u16;
typedef uint32_t u32;
typedef __attribute__((ext_vector_type(8))) short bf16x8;   // 4 VGPRs: MFMA A/B frag
typedef __attribute__((ext_vector_type(4))) float f32x4;    // MFMA C/D frag

__device__ __forceinline__ float bflo(u32 u) { union { u32 i; float f; } v; v.i = u << 16; return v.f; }
__device__ __forceinline__ float bfhi(u32 u) { union { u32 i; float f; } v; v.i = u & 0xffff0000u; return v.f; }
__device__ __forceinline__ u16 f2b(float f) {
    u32 x = __float_as_uint(f);
    return (u16)((x + 0x7fffu + ((x >> 16) & 1u)) >> 16);
}

// ---------------------------------------------------------------------------
// Kernel 1: LayerNorm + Q/K/V projections + bias projection.
// Q/K/V stored HEAD-MAJOR: [H][NP][32] bf16 (coalesced per-head staging in
// k_attn). Q pre-scaled by 1/sqrt(D). bias stored natural [h][j][k] fp32.
// block = 128 threads, 8 positions; grid = 8192.
// ---------------------------------------------------------------------------
__global__ __launch_bounds__(128) void k_ln_qkv(
    const float* __restrict__ pair, const float* __restrict__ ln_g, const float* __restrict__ ln_b,
    const float* __restrict__ Wq, const float* __restrict__ Wk, const float* __restrict__ Wv,
    const float* __restrict__ Wbias,
    u16* __restrict__ qo, u16* __restrict__ ko, u16* __restrict__ vo,
    float* __restrict__ biasB)
{
    __shared__ float zsh[8][C_];
    __shared__ float red[2][4];
    const int t = threadIdx.x;
    const int p0 = blockIdx.x * 8;
    const float g  = ln_g[t];
    const float bb = ln_b[t];

    float xs[8];
    #pragma unroll
    for (int r = 0; r < 8; ++r) xs[r] = pair[(size_t)(p0 + r) * C_ + t];

    #pragma unroll
    for (int r = 0; r < 8; ++r) {
        float x = xs[r];
        float s = x, sq = x * x;
        #pragma unroll
        for (int off = 32; off; off >>= 1) {
            s  += __shfl_down(s, off);
            sq += __shfl_down(sq, off);
        }
        if ((t & 63) == 0) { red[r & 1][t >> 6] = s; red[r & 1][2 + (t >> 6)] = sq; }
        __syncthreads();
        float mu  = (red[r & 1][0] + red[r & 1][1]) * (1.0f / C_);
        float var = (red[r & 1][2] + red[r & 1][3]) * (1.0f / C_) - mu * mu;
        zsh[r][t] = (x - mu) * rsqrtf(fmaxf(var, 0.f) + 1e-5f) * g + bb;
    }
    __syncthreads();

    float aq[8], ak[8], av[8];
    #pragma unroll
    for (int r = 0; r < 8; ++r) { aq[r] = 0.f; ak[r] = 0.f; av[r] = 0.f; }

    for (int c = 0; c < C_; c += 4) {
        float wq[4], wk[4], wv[4];
        #pragma unroll
        for (int u = 0; u < 4; ++u) {
            wq[u] = Wq[(size_t)(c + u) * C_ + t];
            wk[u] = Wk[(size_t)(c + u) * C_ + t];
            wv[u] = Wv[(size_t)(c + u) * C_ + t];
        }
        #pragma unroll
        for (int r = 0; r < 8; ++r) {
            float4 z4 = *(const float4*)&zsh[r][c];
            aq[r] += z4.x * wq[0] + z4.y * wq[1] + z4.z * wq[2] + z4.w * wq[3];
            ak[r] += z4.x * wk[0] + z4.y * wk[1] + z4.z * wk[2] + z4.w * wk[3];
            av[r] += z4.x * wv[0] + z4.y * wv[1] + z4.z * wv[2] + z4.w * wv[3];
        }
    }
    const float scale = 0.17677669529663687f;   // 1/sqrt(32), folded into q
    const int hh = t >> 5, dd = t & 31;
    #pragma unroll
    for (int r = 0; r < 8; ++r) {
        size_t o = ((size_t)hh * NP_ + (p0 + r)) * D_ + dd;   // head-major
        qo[o] = f2b(aq[r] * scale); ko[o] = f2b(ak[r]); vo[o] = f2b(av[r]);
    }

    // bias projection: 32 tasks (8 pos x 4 heads); natural layout biasB[h][j][k]
    if (t < 32) {
        int pos = t >> 2, h = t & 3;
        float a = 0.f;
        for (int c = 0; c < C_; ++c) a += zsh[pos][c] * Wbias[c * H_ + h];
        biasB[(size_t)h * NP_ + (p0 + pos)] = a;    // p = j*256 + k
    }
}

// ---------------------------------------------------------------------------
// Kernel 2 (MFMA REWRITE): attention per (i,h). 256 thr = 4 waves; wave w owns
// q-rows w*64..+63 (4 j-tiles of 16). Per 32-k chunk: 2 S-tile MFMAs
// (16x16x32, K=32=D), bias+exp in C-layout, P -> per-wave LDS (C->A layout
// round-trip, jt-parity double-buffered), 2 PV MFMAs accumulate O.
// qh is Q in / O out in place (per-wave read-before-write, block-exclusive).
// grid = 1024.
// ---------------------------------------------------------------------------
__global__ __launch_bounds__(256) void k_attn(
    u16* __restrict__ qh, const u16* __restrict__ kh, const u16* __restrict__ vh,
    const float* __restrict__ biasB)
{
    __shared__ u16 Ksh[L_][40];        // K rows, pad 32->40 (16B-aligned rows)
    __shared__ u16 Vsh[D_][280];       // V TRANSPOSED [d][k], pad 256->280
    __shared__ u16 Psh[4][2][16][40];  // per-wave, jt-parity double-buffered

    const int t = threadIdx.x;
    const int i = blockIdx.x >> 2;
    const int h = blockIdx.x & 3;
    const int w    = t >> 6;
    const int l15  = t & 15;
    const int quad = (t >> 4) & 3;

    const u16* Kg = kh + ((size_t)h * NP_ + i * L_) * D_;   // 16 KB contiguous
    const u16* Vg = vh + ((size_t)h * NP_ + i * L_) * D_;
    u16*       Qg = qh + ((size_t)h * NP_ + i * L_) * D_;

    // ---- stage K rows (coalesced) ----
    #pragma unroll
    for (int jj = 0; jj < 8; ++jj) {
        int idx = t + jj * 256;           // 0..2047 uint4
        int r = idx >> 2, sg = idx & 3;
        *(uint4*)&Ksh[r][sg * 8] = *(const uint4*)(Kg + r * 32 + sg * 8);
    }
    // ---- stage V transposed (coalesced read, scalar LDS scatter; one-time) ----
    #pragma unroll
    for (int jj = 0; jj < 8; ++jj) {
        int idx = t + jj * 256;
        int r = idx >> 2, sg = idx & 3;
        union { uint4 q; u16 s[8]; } u;
        u.q = *(const uint4*)(Vg + r * 32 + sg * 8);
        #pragma unroll
        for (int m = 0; m < 8; ++m) Vsh[sg * 8 + m][r] = u.s[m];
    }

    // ---- Q A-frags direct from global (q pre-scaled by 1/sqrt(D)) ----
    bf16x8 qf[4];
    #pragma unroll
    for (int jt = 0; jt < 4; ++jt)
        qf[jt] = *(const bf16x8*)(Qg + (size_t)(w * 64 + jt * 16 + l15) * D_ + quad * 8);

    __syncthreads();

    const f32x4 z4 = {0.f, 0.f, 0.f, 0.f};
    f32x4 oacc[4][2];
    float psum[4][4];
    #pragma unroll
    for (int jt = 0; jt < 4; ++jt) {
        oacc[jt][0] = z4; oacc[jt][1] = z4;
        #pragma unroll
        for (int r = 0; r < 4; ++r) psum[jt][r] = 0.f;
    }

    const float* bB = biasB + (size_t)h * NP_;   // [j][k]

    for (int kc = 0; kc < 8; ++kc) {
        bf16x8 kb0 = *(const bf16x8*)&Ksh[kc * 32      + l15][quad * 8];
        bf16x8 kb1 = *(const bf16x8*)&Ksh[kc * 32 + 16 + l15][quad * 8];
        bf16x8 vb0 = *(const bf16x8*)&Vsh[l15     ][kc * 32 + quad * 8];
        bf16x8 vb1 = *(const bf16x8*)&Vsh[16 + l15][kc * 32 + quad * 8];

        #pragma unroll
        for (int jt = 0; jt < 4; ++jt) {
            f32x4 s0 = __builtin_amdgcn_mfma_f32_16x16x32_bf16(qf[jt], kb0, z4, 0, 0, 0);
            f32x4 s1 = __builtin_amdgcn_mfma_f32_16x16x32_bf16(qf[jt], kb1, z4, 0, 0, 0);

            // bias + exp in C-layout: row = quad*4+r, col = l15 (+16 for tile1)
            const float* bp = bB + (size_t)(w * 64 + jt * 16 + quad * 4) * L_ + kc * 32 + l15;
            u16 (*P)[40] = Psh[w][jt & 1];
            float e0[4], e1[4];
            #pragma unroll
            for (int r = 0; r < 4; ++r) {
                e0[r] = __expf(s0[r] + bp[r * L_]);
                e1[r] = __expf(s1[r] + bp[r * L_ + 16]);
                psum[jt][r] += e0[r] + e1[r];
            }
            #pragma unroll
            for (int r = 0; r < 4; ++r) {
                P[quad * 4 + r][l15]      = f2b(e0[r]);
                P[quad * 4 + r][16 + l15] = f2b(e1[r]);
            }
            // C->A layout round-trip (wave-internal; lgkmcnt orders it)
            bf16x8 pa = *(const bf16x8*)&P[l15][quad * 8];
            oacc[jt][0] = __builtin_amdgcn_mfma_f32_16x16x32_bf16(pa, vb0, oacc[jt][0], 0, 0, 0);
            oacc[jt][1] = __builtin_amdgcn_mfma_f32_16x16x32_bf16(pa, vb1, oacc[jt][1], 0, 0, 0);
        }
    }

    // ---- softmax denominators: reduce over 16 cols (lanes of same quad) ----
    float rn[4][4];
    #pragma unroll
    for (int jt = 0; jt < 4; ++jt)
        #pragma unroll
        for (int r = 0; r < 4; ++r) {
            float s = psum[jt][r];
            s += __shfl_xor(s, 1); s += __shfl_xor(s, 2);
            s += __shfl_xor(s, 4); s += __shfl_xor(s, 8);
            rn[jt][r] = 1.f / s;
        }

    // ---- normalize + store O back into qh (head-major) ----
    #pragma unroll
    for (int jt = 0; jt < 4; ++jt) {
        #pragma unroll
        for (int r = 0; r < 4; ++r) {
            size_t row = (size_t)(w * 64 + jt * 16 + quad * 4 + r) * D_;
            Qg[row + l15]      = f2b(oacc[jt][0][r] * rn[jt][r]);
            Qg[row + 16 + l15] = f2b(oacc[jt][1][r] * rn[jt][r]);
        }
    }
}

// ---------------------------------------------------------------------------
// Kernel 3: out = pair + sigmoid(pair@Wg + bg) * (ao@Wo + bo). 512 thr,
// 64 positions staged once in LDS; ao now read from head-major [H][NP][32].
// grid = 1024.
// ---------------------------------------------------------------------------
__global__ __launch_bounds__(512) void k_out(
    const u16* __restrict__ aoh, const float* __restrict__ pair,
    const float* __restrict__ Wo, const float* __restrict__ bo,
    const float* __restrict__ Wg, const float* __restrict__ bg,
    float* __restrict__ out)
{
    __shared__ float zsh[64][132];   // raw pair rows, +4 pad
    __shared__ u16   ash[64][136];   // ao rows bf16 (channel order), +8 pad

    const int t  = threadIdx.x;
    const int p0 = blockIdx.x * 64;

    #pragma unroll
    for (int j = 0; j < 4; ++j) {
        int idx = t + j * 512;            // 0..2047 float4
        int pos = idx >> 5;
        int c   = (idx & 31) * 4;
        *(float4*)&zsh[pos][c] = *(const float4*)(pair + (size_t)(p0 + pos) * C_ + c);
    }
    #pragma unroll
    for (int j = 0; j < 2; ++j) {
        int idx = t + j * 512;            // 0..1023 uint4
        int pos = idx >> 4;
        int seg = idx & 15;               // channel c = seg*8; head = seg>>2
        *(uint4*)&ash[pos][seg * 8] =
            *(const uint4*)(aoh + ((size_t)(seg >> 2) * NP_ + p0 + pos) * D_ + (seg & 3) * 8);
    }
    __syncthreads();

    const int l    = t & 63;
    const int col0 = __builtin_amdgcn_readfirstlane((t >> 6) * 16);

    float accO[16], accG[16];
    #pragma unroll
    for (int u = 0; u < 16; ++u) { accO[u] = 0.f; accG[u] = 0.f; }

    for (int c4 = 0; c4 < C_; c4 += 4) {
        float4 z4 = *(const float4*)&zsh[l][c4];
        uint2  a2 = *(const uint2*)&ash[l][c4];
        float a4[4] = { bflo(a2.x), bfhi(a2.x), bflo(a2.y), bfhi(a2.y) };
        const float* zf = (const float*)&z4;
        #pragma unroll
        for (int cc = 0; cc < 4; ++cc) {
            const float* woP = Wo + (size_t)(c4 + cc) * C_ + col0;  // wave-uniform
            const float* wgP = Wg + (size_t)(c4 + cc) * C_ + col0;  // wave-uniform
            float aa = a4[cc], zz = zf[cc];
            #pragma unroll
            for (int u = 0; u < 4; ++u) {
                float4 wo = *(const float4*)(woP + u * 4);
                float4 wg = *(const float4*)(wgP + u * 4);
                accO[u * 4 + 0] += aa * wo.x;  accG[u * 4 + 0] += zz * wg.x;
                accO[u * 4 + 1] += aa * wo.y;  accG[u * 4 + 1] += zz * wg.y;
                accO[u * 4 + 2] += aa * wo.z;  accG[u * 4 + 2] += zz * wg.z;
                accO[u * 4 + 3] += aa * wo.w;  accG[u * 4 + 3] += zz * wg.w;
            }
        }
    }

    float* dst = out + (size_t)(p0 + l) * C_ + col0;
    #pragma unroll
    for (int u = 0; u < 4; ++u) {
        float4 bo4 = *(const float4*)(bo + col0 + u * 4);
        float4 bg4 = *(const float4*)(bg + col0 + u * 4);
        float4 pz  = *(const float4*)&zsh[l][col0 + u * 4];
        float4 r;
        float o0 = accO[u*4+0] + bo4.x, g0 = accG[u*4+0] + bg4.x;
        float o1 = accO[u*4+1] + bo4.y, g1 = accG[u*4+1] + bg4.y;
        float o2 = accO[u*4+2] + bo4.z, g2 = accG[u*4+2] + bg4.z;
        float o3 = accO[u*4+3] + bo4.w, g3 = accG[u*4+3] + bg4.w;
        r.x = pz.x + (1.f / (1.f + __expf(-g0))) * o0;
        r.y = pz.y + (1.f / (1.f + __expf(-g1))) * o1;
        r.z = pz.z + (1.f / (1.f + __expf(-g2))) * o2;
        r.w = pz.w + (1.f / (1.f + __expf(-g3))) * o3;
        *(float4*)(dst + u * 4) = r;
    }
}

// ---------------------------------------------------------------------------
// Workspace layout (49 MB):
//   [0,  1 MB)  biasB  fp32 [H][j][k]
//   [1, 17 MB)  qh     bf16 [H][NP][32]  (Q in, O out in place)
//   [17,33 MB)  kh     bf16 [H][NP][32]
//   [33,49 MB)  vh     bf16 [H][NP][32]
// ---------------------------------------------------------------------------
extern "C" void kernel_launch(void* const* d_in, const int* in_sizes, int n_in,
                              void* d_out, int out_size, void* d_ws, size_t ws_size,
                              hipStream_t stream) {
    const float* pair  = (const float*)d_in[0];
    const float* ln_g  = (const float*)d_in[1];
    const float* ln_b  = (const float*)d_in[2];
    const float* Wq    = (const float*)d_in[3];
    const float* Wk    = (const float*)d_in[4];
    const float* Wv    = (const float*)d_in[5];
    const float* Wbias = (const float*)d_in[6];
    const float* Wo    = (const float*)d_in[7];
    const float* bo    = (const float*)d_in[8];
    const float* Wg    = (const float*)d_in[9];
    const float* bg    = (const float*)d_in[10];
    float* out = (float*)d_out;

    float* biasB = (float*)d_ws;
    u16* qh = (u16*)(biasB + (size_t)H_ * NP_);
    u16* kh = qh + (size_t)NP_ * C_;
    u16* vh = kh + (size_t)NP_ * C_;

    k_ln_qkv<<<NP_ / 8, 128, 0, stream>>>(pair, ln_g, ln_b, Wq, Wk, Wv, Wbias, qh, kh, vh, biasB);
    k_attn<<<L_ * H_, 256, 0, stream>>>(qh, kh, vh, biasB);
    k_out<<<NP_ / 64, 512, 0, stream>>>(qh, pair, Wo, bo, Wg, bg, out);
}

// Round 6
// 270.598 us; speedup vs baseline: 3.9990x; 1.2732x over previous
//
#include <hip/hip_runtime.h>
#include <cstdint>
#include <cstddef>

#define L_ 256
#define C_ 128
#define H_ 4
#define D_ 32
#define NP_ (L_ * L_)

typedef unsigned short u16;
typedef uint32_t u32;
typedef __attribute__((ext_vector_type(8))) short bf16x8;   // 4 VGPRs: MFMA A/B frag
typedef __attribute__((ext_vector_type(4))) float f32x4;    // MFMA C/D frag

__device__ __forceinline__ float bflo(u32 u) { union { u32 i; float f; } v; v.i = u << 16; return v.f; }
__device__ __forceinline__ float bfhi(u32 u) { union { u32 i; float f; } v; v.i = u & 0xffff0000u; return v.f; }
__device__ __forceinline__ u16 f2b(float f) {
    u32 x = __float_as_uint(f);
    return (u16)((x + 0x7fffu + ((x >> 16) & 1u)) >> 16);
}
__device__ __forceinline__ u32 pk2(float lo, float hi) {
    return ((u32)f2b(hi) << 16) | (u32)f2b(lo);
}

// ---------------------------------------------------------------------------
// Kernel 0: weight prep (runs every launch; ~200 KB of traffic).
//   Wt[mat][n][c] (bf16) = W_mat[c][n]  (mat 0 = Wq, scaled by 1/sqrt(D))
//   WbT[h][c]     (fp32) = Wbias[c][h]
// grid = 49 blocks x 256 thr.
// ---------------------------------------------------------------------------
__global__ __launch_bounds__(256) void k_prep(
    const float* __restrict__ Wq, const float* __restrict__ Wk, const float* __restrict__ Wv,
    const float* __restrict__ Wbias, u16* __restrict__ Wt, float* __restrict__ WbT)
{
    const int b = blockIdx.x;
    if (b < 48) {
        const int mat = b >> 4, sub = b & 15;
        const float* W = (mat == 0) ? Wq : ((mat == 1) ? Wk : Wv);
        const float s = (mat == 0) ? 0.17677669529663687f : 1.f;
        #pragma unroll
        for (int m = 0; m < 4; ++m) {
            int idx = sub * 1024 + m * 256 + threadIdx.x;    // 0..16383
            int n = idx >> 7, c = idx & 127;
            Wt[mat * 16384 + idx] = f2b(W[c * 128 + n] * s);
        }
    } else {
        #pragma unroll
        for (int m = 0; m < 2; ++m) {
            int idx = m * 256 + threadIdx.x;                 // 0..511
            int h = idx >> 7, c = idx & 127;
            WbT[h * 128 + c] = Wbias[c * H_ + h];
        }
    }
}

// ---------------------------------------------------------------------------
// Kernel 1 (MFMA REWRITE): LayerNorm + Q/K/V projections + bias projection.
// Block = 256 thr (4 waves), 64 positions; grid = 1024.
//  - pair staged coalesced into LDS fp32; LN with 4 lanes/row (shfl combine);
//    z packed to bf16 LDS [64][144].
//  - GEMM as D = Wt · z^T (16x16x32 MFMA): A-frag = Wt rows (global, L2-hot),
//    B-frag = z^T from LDS (loaded ONCE, 4 b128/thread). C-layout then gives
//    each thread 4 consecutive output channels -> packed uint2 stores into
//    head-major qh/kh/vh, no repack.
//  - bias proj (N=4) on VALU from zsh + WbT.
// ---------------------------------------------------------------------------
__global__ __launch_bounds__(256) void k_lnmm(
    const float* __restrict__ pair, const float* __restrict__ ln_g, const float* __restrict__ ln_b,
    const u16* __restrict__ Wt, const float* __restrict__ WbT,
    u16* __restrict__ qh, u16* __restrict__ kh, u16* __restrict__ vh,
    float* __restrict__ biasB)
{
    __shared__ float psh[64][132];    // pair rows fp32, +4 pad
    __shared__ u16   zsh[64][144];    // z rows bf16, stride 288 B (16B-aligned)

    const int t  = threadIdx.x;
    const int p0 = blockIdx.x * 64;

    // ---- stage 64 pair rows (2048 float4, coalesced) ----
    #pragma unroll
    for (int j = 0; j < 8; ++j) {
        int idx = t + j * 256;
        int row = idx >> 5, c4 = (idx & 31) * 4;
        *(float4*)&psh[row][c4] = *(const float4*)(pair + (size_t)(p0 + row) * C_ + c4);
    }
    __syncthreads();

    // ---- LayerNorm: 4 lanes per row, 32 channels each (interleaved slots) ----
    const int row = t >> 2, seg = t & 3;
    float4 xv[8];
    float sum = 0.f, ss = 0.f;
    #pragma unroll
    for (int i = 0; i < 8; ++i) {
        int c = (seg + 4 * i) * 4;
        float4 x = *(const float4*)&psh[row][c];
        xv[i] = x;
        sum += x.x + x.y + x.z + x.w;
        ss  += x.x * x.x + x.y * x.y + x.z * x.z + x.w * x.w;
    }
    sum += __shfl_xor(sum, 1); sum += __shfl_xor(sum, 2);
    ss  += __shfl_xor(ss, 1);  ss  += __shfl_xor(ss, 2);
    float mu  = sum * (1.0f / C_);
    float var = ss * (1.0f / C_) - mu * mu;
    float rs  = rsqrtf(fmaxf(var, 0.f) + 1e-5f);

    #pragma unroll
    for (int i = 0; i < 8; ++i) {
        int c = (seg + 4 * i) * 4;
        float4 g4 = *(const float4*)(ln_g + c);
        float4 b4 = *(const float4*)(ln_b + c);
        float4 x  = xv[i];
        float z0 = (x.x - mu) * rs * g4.x + b4.x;
        float z1 = (x.y - mu) * rs * g4.y + b4.y;
        float z2 = (x.z - mu) * rs * g4.z + b4.z;
        float z3 = (x.w - mu) * rs * g4.w + b4.w;
        *(u32*)&zsh[row][c]     = pk2(z0, z1);
        *(u32*)&zsh[row][c + 2] = pk2(z2, z3);
    }
    // everything below is wave-local: zsh rows w*16..+15 written by wave w only

    const int w    = t >> 6;
    const int l15  = t & 15;
    const int quad = (t >> 4) & 3;
    const int p    = p0 + w * 16 + l15;

    // ---- z^T B-frags: loaded once ----
    bf16x8 zf[4];
    #pragma unroll
    for (int kc = 0; kc < 4; ++kc)
        zf[kc] = *(const bf16x8*)&zsh[w * 16 + l15][kc * 32 + quad * 8];

    // ---- 3 GEMMs: D = Wt . z^T ----
    u16* const dsts[3] = { qh, kh, vh };
    #pragma unroll
    for (int mat = 0; mat < 3; ++mat) {
        u16* dst = dsts[mat];
        const u16* Wm = Wt + mat * 16384;
        #pragma unroll
        for (int mt = 0; mt < 8; ++mt) {
            f32x4 acc = {0.f, 0.f, 0.f, 0.f};
            #pragma unroll
            for (int kc = 0; kc < 4; ++kc) {
                bf16x8 af = *(const bf16x8*)(Wm + (size_t)(mt * 16 + l15) * 128 + kc * 32 + quad * 8);
                acc = __builtin_amdgcn_mfma_f32_16x16x32_bf16(af, zf[kc], acc, 0, 0, 0);
            }
            // C-layout: n-channel = mt*16 + quad*4 + r (4 consecutive), row = p
            int hh = mt >> 1;
            int cb = (mt & 1) * 16 + quad * 4;
            *(uint2*)(dst + ((size_t)hh * NP_ + p) * D_ + cb) =
                make_uint2(pk2(acc[0], acc[1]), pk2(acc[2], acc[3]));
        }
    }

    // ---- bias projection: thread (row, h) ----
    {
        const int h = seg;   // t&3
        float a = 0.f;
        #pragma unroll
        for (int c8 = 0; c8 < C_; c8 += 8) {
            uint4 zz = *(const uint4*)&zsh[row][c8];        // broadcast across 4 lanes
            float4 wb0 = *(const float4*)(WbT + h * 128 + c8);
            float4 wb1 = *(const float4*)(WbT + h * 128 + c8 + 4);
            a += bflo(zz.x) * wb0.x + bfhi(zz.x) * wb0.y
               + bflo(zz.y) * wb0.z + bfhi(zz.y) * wb0.w
               + bflo(zz.z) * wb1.x + bfhi(zz.z) * wb1.y
               + bflo(zz.w) * wb1.z + bfhi(zz.w) * wb1.w;
        }
        biasB[(size_t)h * NP_ + p0 + row] = a;
    }
}

// ---------------------------------------------------------------------------
// Kernel 2: attention per (i,h). (unchanged from round 5)
// ---------------------------------------------------------------------------
__global__ __launch_bounds__(256) void k_attn(
    u16* __restrict__ qh, const u16* __restrict__ kh, const u16* __restrict__ vh,
    const float* __restrict__ biasB)
{
    __shared__ u16 Ksh[L_][40];
    __shared__ u16 Vsh[D_][280];
    __shared__ u16 Psh[4][2][16][40];

    const int t = threadIdx.x;
    const int i = blockIdx.x >> 2;
    const int h = blockIdx.x & 3;
    const int w    = t >> 6;
    const int l15  = t & 15;
    const int quad = (t >> 4) & 3;

    const u16* Kg = kh + ((size_t)h * NP_ + i * L_) * D_;
    const u16* Vg = vh + ((size_t)h * NP_ + i * L_) * D_;
    u16*       Qg = qh + ((size_t)h * NP_ + i * L_) * D_;

    #pragma unroll
    for (int jj = 0; jj < 8; ++jj) {
        int idx = t + jj * 256;
        int r = idx >> 2, sg = idx & 3;
        *(uint4*)&Ksh[r][sg * 8] = *(const uint4*)(Kg + r * 32 + sg * 8);
    }
    #pragma unroll
    for (int jj = 0; jj < 8; ++jj) {
        int idx = t + jj * 256;
        int r = idx >> 2, sg = idx & 3;
        union { uint4 q; u16 s[8]; } u;
        u.q = *(const uint4*)(Vg + r * 32 + sg * 8);
        #pragma unroll
        for (int m = 0; m < 8; ++m) Vsh[sg * 8 + m][r] = u.s[m];
    }

    bf16x8 qf[4];
    #pragma unroll
    for (int jt = 0; jt < 4; ++jt)
        qf[jt] = *(const bf16x8*)(Qg + (size_t)(w * 64 + jt * 16 + l15) * D_ + quad * 8);

    __syncthreads();

    const f32x4 z4 = {0.f, 0.f, 0.f, 0.f};
    f32x4 oacc[4][2];
    float psum[4][4];
    #pragma unroll
    for (int jt = 0; jt < 4; ++jt) {
        oacc[jt][0] = z4; oacc[jt][1] = z4;
        #pragma unroll
        for (int r = 0; r < 4; ++r) psum[jt][r] = 0.f;
    }

    const float* bB = biasB + (size_t)h * NP_;

    for (int kc = 0; kc < 8; ++kc) {
        bf16x8 kb0 = *(const bf16x8*)&Ksh[kc * 32      + l15][quad * 8];
        bf16x8 kb1 = *(const bf16x8*)&Ksh[kc * 32 + 16 + l15][quad * 8];
        bf16x8 vb0 = *(const bf16x8*)&Vsh[l15     ][kc * 32 + quad * 8];
        bf16x8 vb1 = *(const bf16x8*)&Vsh[16 + l15][kc * 32 + quad * 8];

        #pragma unroll
        for (int jt = 0; jt < 4; ++jt) {
            f32x4 s0 = __builtin_amdgcn_mfma_f32_16x16x32_bf16(qf[jt], kb0, z4, 0, 0, 0);
            f32x4 s1 = __builtin_amdgcn_mfma_f32_16x16x32_bf16(qf[jt], kb1, z4, 0, 0, 0);

            const float* bp = bB + (size_t)(w * 64 + jt * 16 + quad * 4) * L_ + kc * 32 + l15;
            u16 (*P)[40] = Psh[w][jt & 1];
            float e0[4], e1[4];
            #pragma unroll
            for (int r = 0; r < 4; ++r) {
                e0[r] = __expf(s0[r] + bp[r * L_]);
                e1[r] = __expf(s1[r] + bp[r * L_ + 16]);
                psum[jt][r] += e0[r] + e1[r];
            }
            #pragma unroll
            for (int r = 0; r < 4; ++r) {
                P[quad * 4 + r][l15]      = f2b(e0[r]);
                P[quad * 4 + r][16 + l15] = f2b(e1[r]);
            }
            bf16x8 pa = *(const bf16x8*)&P[l15][quad * 8];
            oacc[jt][0] = __builtin_amdgcn_mfma_f32_16x16x32_bf16(pa, vb0, oacc[jt][0], 0, 0, 0);
            oacc[jt][1] = __builtin_amdgcn_mfma_f32_16x16x32_bf16(pa, vb1, oacc[jt][1], 0, 0, 0);
        }
    }

    float rn[4][4];
    #pragma unroll
    for (int jt = 0; jt < 4; ++jt)
        #pragma unroll
        for (int r = 0; r < 4; ++r) {
            float s = psum[jt][r];
            s += __shfl_xor(s, 1); s += __shfl_xor(s, 2);
            s += __shfl_xor(s, 4); s += __shfl_xor(s, 8);
            rn[jt][r] = 1.f / s;
        }

    #pragma unroll
    for (int jt = 0; jt < 4; ++jt) {
        #pragma unroll
        for (int r = 0; r < 4; ++r) {
            size_t rowo = (size_t)(w * 64 + jt * 16 + quad * 4 + r) * D_;
            Qg[rowo + l15]      = f2b(oacc[jt][0][r] * rn[jt][r]);
            Qg[rowo + 16 + l15] = f2b(oacc[jt][1][r] * rn[jt][r]);
        }
    }
}

// ---------------------------------------------------------------------------
// Kernel 3: out = pair + sigmoid(pair@Wg + bg) * (ao@Wo + bo). (unchanged)
// ---------------------------------------------------------------------------
__global__ __launch_bounds__(512) void k_out(
    const u16* __restrict__ aoh, const float* __restrict__ pair,
    const float* __restrict__ Wo, const float* __restrict__ bo,
    const float* __restrict__ Wg, const float* __restrict__ bg,
    float* __restrict__ out)
{
    __shared__ float zsh[64][132];
    __shared__ u16   ash[64][136];

    const int t  = threadIdx.x;
    const int p0 = blockIdx.x * 64;

    #pragma unroll
    for (int j = 0; j < 4; ++j) {
        int idx = t + j * 512;
        int pos = idx >> 5;
        int c   = (idx & 31) * 4;
        *(float4*)&zsh[pos][c] = *(const float4*)(pair + (size_t)(p0 + pos) * C_ + c);
    }
    #pragma unroll
    for (int j = 0; j < 2; ++j) {
        int idx = t + j * 512;
        int pos = idx >> 4;
        int seg = idx & 15;
        *(uint4*)&ash[pos][seg * 8] =
            *(const uint4*)(aoh + ((size_t)(seg >> 2) * NP_ + p0 + pos) * D_ + (seg & 3) * 8);
    }
    __syncthreads();

    const int l    = t & 63;
    const int col0 = __builtin_amdgcn_readfirstlane((t >> 6) * 16);

    float accO[16], accG[16];
    #pragma unroll
    for (int u = 0; u < 16; ++u) { accO[u] = 0.f; accG[u] = 0.f; }

    for (int c4 = 0; c4 < C_; c4 += 4) {
        float4 z4 = *(const float4*)&zsh[l][c4];
        uint2  a2 = *(const uint2*)&ash[l][c4];
        float a4[4] = { bflo(a2.x), bfhi(a2.x), bflo(a2.y), bfhi(a2.y) };
        const float* zf = (const float*)&z4;
        #pragma unroll
        for (int cc = 0; cc < 4; ++cc) {
            const float* woP = Wo + (size_t)(c4 + cc) * C_ + col0;
            const float* wgP = Wg + (size_t)(c4 + cc) * C_ + col0;
            float aa = a4[cc], zz = zf[cc];
            #pragma unroll
            for (int u = 0; u < 4; ++u) {
                float4 wo = *(const float4*)(woP + u * 4);
                float4 wg = *(const float4*)(wgP + u * 4);
                accO[u * 4 + 0] += aa * wo.x;  accG[u * 4 + 0] += zz * wg.x;
                accO[u * 4 + 1] += aa * wo.y;  accG[u * 4 + 1] += zz * wg.y;
                accO[u * 4 + 2] += aa * wo.z;  accG[u * 4 + 2] += zz * wg.z;
                accO[u * 4 + 3] += aa * wo.w;  accG[u * 4 + 3] += zz * wg.w;
            }
        }
    }

    float* dst = out + (size_t)(p0 + l) * C_ + col0;
    #pragma unroll
    for (int u = 0; u < 4; ++u) {
        float4 bo4 = *(const float4*)(bo + col0 + u * 4);
        float4 bg4 = *(const float4*)(bg + col0 + u * 4);
        float4 pz  = *(const float4*)&zsh[l][col0 + u * 4];
        float4 r;
        float o0 = accO[u*4+0] + bo4.x, g0 = accG[u*4+0] + bg4.x;
        float o1 = accO[u*4+1] + bo4.y, g1 = accG[u*4+1] + bg4.y;
        float o2 = accO[u*4+2] + bo4.z, g2 = accG[u*4+2] + bg4.z;
        float o3 = accO[u*4+3] + bo4.w, g3 = accG[u*4+3] + bg4.w;
        r.x = pz.x + (1.f / (1.f + __expf(-g0))) * o0;
        r.y = pz.y + (1.f / (1.f + __expf(-g1))) * o1;
        r.z = pz.z + (1.f / (1.f + __expf(-g2))) * o2;
        r.w = pz.w + (1.f / (1.f + __expf(-g3))) * o3;
        *(float4*)(dst + u * 4) = r;
    }
}

// ---------------------------------------------------------------------------
// Workspace (49.1 MB):
//   [0, 1 MB)    biasB fp32 [H][j][k]
//   [1, 17 MB)   qh bf16 [H][NP][32]  (Q in, O out in place)
//   [17, 33 MB)  kh bf16
//   [33, 49 MB)  vh bf16
//   [49 MB, +96K) Wt bf16 [3][128][128]   (transposed weights)
//   [.., +2K)    WbT fp32 [4][128]
// ---------------------------------------------------------------------------
extern "C" void kernel_launch(void* const* d_in, const int* in_sizes, int n_in,
                              void* d_out, int out_size, void* d_ws, size_t ws_size,
                              hipStream_t stream) {
    const float* pair  = (const float*)d_in[0];
    const float* ln_g  = (const float*)d_in[1];
    const float* ln_b  = (const float*)d_in[2];
    const float* Wq    = (const float*)d_in[3];
    const float* Wk    = (const float*)d_in[4];
    const float* Wv    = (const float*)d_in[5];
    const float* Wbias = (const float*)d_in[6];
    const float* Wo    = (const float*)d_in[7];
    const float* bo    = (const float*)d_in[8];
    const float* Wg    = (const float*)d_in[9];
    const float* bg    = (const float*)d_in[10];
    float* out = (float*)d_out;

    float* biasB = (float*)d_ws;
    u16* qh = (u16*)(biasB + (size_t)H_ * NP_);
    u16* kh = qh + (size_t)NP_ * C_;
    u16* vh = kh + (size_t)NP_ * C_;
    u16* Wt = vh + (size_t)NP_ * C_;
    float* WbT = (float*)(Wt + 3 * 16384);

    k_prep<<<49, 256, 0, stream>>>(Wq, Wk, Wv, Wbias, Wt, WbT);
    k_lnmm<<<NP_ / 64, 256, 0, stream>>>(pair, ln_g, ln_b, Wt, WbT, qh, kh, vh, biasB);
    k_attn<<<L_ * H_, 256, 0, stream>>>(qh, kh, vh, biasB);
    k_out<<<NP_ / 64, 512, 0, stream>>>(qh, pair, Wo, bo, Wg, bg, out);
}

// Round 7
// 258.990 us; speedup vs baseline: 4.1782x; 1.0448x over previous
//
#include <hip/hip_runtime.h>
#include <cstdint>
#include <cstddef>

#define L_ 256
#define C_ 128
#define H_ 4
#define D_ 32
#define NP_ (L_ * L_)

typedef unsigned short u16;
typedef uint32_t u32;
typedef __attribute__((ext_vector_type(8))) short bf16x8;   // 4 VGPRs: MFMA A/B frag
typedef __attribute__((ext_vector_type(4))) float f32x4;    // MFMA C/D frag

__device__ __forceinline__ float bflo(u32 u) { union { u32 i; float f; } v; v.i = u << 16; return v.f; }
__device__ __forceinline__ float bfhi(u32 u) { union { u32 i; float f; } v; v.i = u & 0xffff0000u; return v.f; }
__device__ __forceinline__ u16 f2b(float f) {
    u32 x = __float_as_uint(f);
    return (u16)((x + 0x7fffu + ((x >> 16) & 1u)) >> 16);
}
__device__ __forceinline__ u32 pk2(float lo, float hi) {
    return ((u32)f2b(hi) << 16) | (u32)f2b(lo);
}
__device__ __forceinline__ bf16x8 pack8(float4 a, float4 b) {
    union { u32 u[4]; bf16x8 v; } r;
    r.u[0] = pk2(a.x, a.y); r.u[1] = pk2(a.z, a.w);
    r.u[2] = pk2(b.x, b.y); r.u[3] = pk2(b.z, b.w);
    return r.v;
}

// ---------------------------------------------------------------------------
// Kernel 0: weight prep. Wt[mat][n][c] (bf16) = W_mat[c][n] for
// mat = {Wq(*1/sqrt(D)), Wk, Wv, Wo, Wg}; WbT[h][c] = Wbias[c][h] (fp32).
// grid = 81 x 256.
// ---------------------------------------------------------------------------
__global__ __launch_bounds__(256) void k_prep(
    const float* __restrict__ Wq, const float* __restrict__ Wk, const float* __restrict__ Wv,
    const float* __restrict__ Wo, const float* __restrict__ Wg,
    const float* __restrict__ Wbias, u16* __restrict__ Wt, float* __restrict__ WbT)
{
    const int b = blockIdx.x;
    if (b < 80) {
        const int mat = b >> 4, sub = b & 15;
        const float* W = (mat == 0) ? Wq : (mat == 1) ? Wk : (mat == 2) ? Wv : (mat == 3) ? Wo : Wg;
        const float s = (mat == 0) ? 0.17677669529663687f : 1.f;
        #pragma unroll
        for (int m = 0; m < 4; ++m) {
            int idx = sub * 1024 + m * 256 + threadIdx.x;    // 0..16383
            int n = idx >> 7, c = idx & 127;
            Wt[mat * 16384 + idx] = f2b(W[c * 128 + n] * s);
        }
    } else {
        #pragma unroll
        for (int m = 0; m < 2; ++m) {
            int idx = m * 256 + threadIdx.x;                 // 0..511
            int h = idx >> 7, c = idx & 127;
            WbT[h * 128 + c] = Wbias[c * H_ + h];
        }
    }
}

// ---------------------------------------------------------------------------
// Kernel 1: LayerNorm + Q/K/V projections + bias projection.
// Block = 128 thr (2 waves), 32 rows; grid = 2048. NO pair staging LDS (direct
// interleaved global loads), NO barrier (zsh rows are wave-local: rows
// w*16..+15 written and read only by wave w). LDS = 9 KB -> high occupancy.
// ---------------------------------------------------------------------------
__global__ __launch_bounds__(128) void k_lnmm(
    const float* __restrict__ pair, const float* __restrict__ ln_g, const float* __restrict__ ln_b,
    const u16* __restrict__ Wt, const float* __restrict__ WbT,
    u16* __restrict__ qh, u16* __restrict__ kh, u16* __restrict__ vh,
    float* __restrict__ biasB)
{
    __shared__ u16 zsh[32][144];      // z rows bf16, stride 288 B

    const int t  = threadIdx.x;
    const int p0 = blockIdx.x * 32;
    const int row = t >> 2, seg = t & 3;

    // ---- LN: 4 lanes/row, interleaved float4 slots (64 B/row/instr coalescing) ----
    float4 xv[8];
    float sum = 0.f, ss = 0.f;
    #pragma unroll
    for (int i = 0; i < 8; ++i) {
        int c = (seg + 4 * i) * 4;
        float4 x = *(const float4*)(pair + (size_t)(p0 + row) * C_ + c);
        xv[i] = x;
        sum += x.x + x.y + x.z + x.w;
        ss  += x.x * x.x + x.y * x.y + x.z * x.z + x.w * x.w;
    }
    sum += __shfl_xor(sum, 1); sum += __shfl_xor(sum, 2);
    ss  += __shfl_xor(ss, 1);  ss  += __shfl_xor(ss, 2);
    float mu  = sum * (1.0f / C_);
    float var = ss * (1.0f / C_) - mu * mu;
    float rs  = rsqrtf(fmaxf(var, 0.f) + 1e-5f);

    #pragma unroll
    for (int i = 0; i < 8; ++i) {
        int c = (seg + 4 * i) * 4;
        float4 g4 = *(const float4*)(ln_g + c);
        float4 b4 = *(const float4*)(ln_b + c);
        float4 x  = xv[i];
        float z0 = (x.x - mu) * rs * g4.x + b4.x;
        float z1 = (x.y - mu) * rs * g4.y + b4.y;
        float z2 = (x.z - mu) * rs * g4.z + b4.z;
        float z3 = (x.w - mu) * rs * g4.w + b4.w;
        *(u32*)&zsh[row][c]     = pk2(z0, z1);
        *(u32*)&zsh[row][c + 2] = pk2(z2, z3);
    }
    // wave-local from here (no __syncthreads): wave w reads rows w*16..+15 only

    const int w    = t >> 6;
    const int l15  = t & 15;
    const int quad = (t >> 4) & 3;
    const int p    = p0 + w * 16 + l15;

    bf16x8 zf[4];
    #pragma unroll
    for (int kc = 0; kc < 4; ++kc)
        zf[kc] = *(const bf16x8*)&zsh[w * 16 + l15][kc * 32 + quad * 8];

    u16* const dsts[3] = { qh, kh, vh };
    #pragma unroll
    for (int mat = 0; mat < 3; ++mat) {
        u16* dst = dsts[mat];
        const u16* Wm = Wt + mat * 16384;
        #pragma unroll
        for (int mt = 0; mt < 8; ++mt) {
            f32x4 acc = {0.f, 0.f, 0.f, 0.f};
            #pragma unroll
            for (int kc = 0; kc < 4; ++kc) {
                bf16x8 af = *(const bf16x8*)(Wm + (size_t)(mt * 16 + l15) * 128 + kc * 32 + quad * 8);
                acc = __builtin_amdgcn_mfma_f32_16x16x32_bf16(af, zf[kc], acc, 0, 0, 0);
            }
            int hh = mt >> 1;
            int cb = (mt & 1) * 16 + quad * 4;
            *(uint2*)(dst + ((size_t)hh * NP_ + p) * D_ + cb) =
                make_uint2(pk2(acc[0], acc[1]), pk2(acc[2], acc[3]));
        }
    }

    // ---- bias projection: thread (row, h=seg) ----
    {
        float a = 0.f;
        #pragma unroll
        for (int c8 = 0; c8 < C_; c8 += 8) {
            uint4 zz = *(const uint4*)&zsh[row][c8];
            float4 wb0 = *(const float4*)(WbT + seg * 128 + c8);
            float4 wb1 = *(const float4*)(WbT + seg * 128 + c8 + 4);
            a += bflo(zz.x) * wb0.x + bfhi(zz.x) * wb0.y
               + bflo(zz.y) * wb0.z + bfhi(zz.y) * wb0.w
               + bflo(zz.z) * wb1.x + bfhi(zz.z) * wb1.y
               + bflo(zz.w) * wb1.z + bfhi(zz.w) * wb1.w;
        }
        biasB[(size_t)seg * NP_ + p0 + row] = a;
    }
}

// ---------------------------------------------------------------------------
// Kernel 2: attention per (i,h). (unchanged from round 6)
// ---------------------------------------------------------------------------
__global__ __launch_bounds__(256) void k_attn(
    u16* __restrict__ qh, const u16* __restrict__ kh, const u16* __restrict__ vh,
    const float* __restrict__ biasB)
{
    __shared__ u16 Ksh[L_][40];
    __shared__ u16 Vsh[D_][280];
    __shared__ u16 Psh[4][2][16][40];

    const int t = threadIdx.x;
    const int i = blockIdx.x >> 2;
    const int h = blockIdx.x & 3;
    const int w    = t >> 6;
    const int l15  = t & 15;
    const int quad = (t >> 4) & 3;

    const u16* Kg = kh + ((size_t)h * NP_ + i * L_) * D_;
    const u16* Vg = vh + ((size_t)h * NP_ + i * L_) * D_;
    u16*       Qg = qh + ((size_t)h * NP_ + i * L_) * D_;

    #pragma unroll
    for (int jj = 0; jj < 8; ++jj) {
        int idx = t + jj * 256;
        int r = idx >> 2, sg = idx & 3;
        *(uint4*)&Ksh[r][sg * 8] = *(const uint4*)(Kg + r * 32 + sg * 8);
    }
    #pragma unroll
    for (int jj = 0; jj < 8; ++jj) {
        int idx = t + jj * 256;
        int r = idx >> 2, sg = idx & 3;
        union { uint4 q; u16 s[8]; } u;
        u.q = *(const uint4*)(Vg + r * 32 + sg * 8);
        #pragma unroll
        for (int m = 0; m < 8; ++m) Vsh[sg * 8 + m][r] = u.s[m];
    }

    bf16x8 qf[4];
    #pragma unroll
    for (int jt = 0; jt < 4; ++jt)
        qf[jt] = *(const bf16x8*)(Qg + (size_t)(w * 64 + jt * 16 + l15) * D_ + quad * 8);

    __syncthreads();

    const f32x4 z4 = {0.f, 0.f, 0.f, 0.f};
    f32x4 oacc[4][2];
    float psum[4][4];
    #pragma unroll
    for (int jt = 0; jt < 4; ++jt) {
        oacc[jt][0] = z4; oacc[jt][1] = z4;
        #pragma unroll
        for (int r = 0; r < 4; ++r) psum[jt][r] = 0.f;
    }

    const float* bB = biasB + (size_t)h * NP_;

    for (int kc = 0; kc < 8; ++kc) {
        bf16x8 kb0 = *(const bf16x8*)&Ksh[kc * 32      + l15][quad * 8];
        bf16x8 kb1 = *(const bf16x8*)&Ksh[kc * 32 + 16 + l15][quad * 8];
        bf16x8 vb0 = *(const bf16x8*)&Vsh[l15     ][kc * 32 + quad * 8];
        bf16x8 vb1 = *(const bf16x8*)&Vsh[16 + l15][kc * 32 + quad * 8];

        #pragma unroll
        for (int jt = 0; jt < 4; ++jt) {
            f32x4 s0 = __builtin_amdgcn_mfma_f32_16x16x32_bf16(qf[jt], kb0, z4, 0, 0, 0);
            f32x4 s1 = __builtin_amdgcn_mfma_f32_16x16x32_bf16(qf[jt], kb1, z4, 0, 0, 0);

            const float* bp = bB + (size_t)(w * 64 + jt * 16 + quad * 4) * L_ + kc * 32 + l15;
            u16 (*P)[40] = Psh[w][jt & 1];
            float e0[4], e1[4];
            #pragma unroll
            for (int r = 0; r < 4; ++r) {
                e0[r] = __expf(s0[r] + bp[r * L_]);
                e1[r] = __expf(s1[r] + bp[r * L_ + 16]);
                psum[jt][r] += e0[r] + e1[r];
            }
            #pragma unroll
            for (int r = 0; r < 4; ++r) {
                P[quad * 4 + r][l15]      = f2b(e0[r]);
                P[quad * 4 + r][16 + l15] = f2b(e1[r]);
            }
            bf16x8 pa = *(const bf16x8*)&P[l15][quad * 8];
            oacc[jt][0] = __builtin_amdgcn_mfma_f32_16x16x32_bf16(pa, vb0, oacc[jt][0], 0, 0, 0);
            oacc[jt][1] = __builtin_amdgcn_mfma_f32_16x16x32_bf16(pa, vb1, oacc[jt][1], 0, 0, 0);
        }
    }

    float rn[4][4];
    #pragma unroll
    for (int jt = 0; jt < 4; ++jt)
        #pragma unroll
        for (int r = 0; r < 4; ++r) {
            float s = psum[jt][r];
            s += __shfl_xor(s, 1); s += __shfl_xor(s, 2);
            s += __shfl_xor(s, 4); s += __shfl_xor(s, 8);
            rn[jt][r] = 1.f / s;
        }

    #pragma unroll
    for (int jt = 0; jt < 4; ++jt) {
        #pragma unroll
        for (int r = 0; r < 4; ++r) {
            size_t rowo = (size_t)(w * 64 + jt * 16 + quad * 4 + r) * D_;
            Qg[rowo + l15]      = f2b(oacc[jt][0][r] * rn[jt][r]);
            Qg[rowo + 16 + l15] = f2b(oacc[jt][1][r] * rn[jt][r]);
        }
    }
}

// ---------------------------------------------------------------------------
// Kernel 3 (MFMA REWRITE): out = pair + sigmoid(pair@Wg+bg) * (ao@Wo+bo).
// Block = 256 thr (4 waves), 64 rows; grid = 1024. NO LDS, NO barrier.
// Per wave (16 rows): B-frags = ao rows (head-major, contiguous 16 B) and
// pair rows packed fp32->bf16 in-register; A-frags = WoT/WgT bf16 (L2-hot).
// D = W^T . x^T: C-layout -> each thread owns 4 consecutive out channels of
// row l15 -> fused float4 epilogue (bias, sigmoid, residual).
// ---------------------------------------------------------------------------
__global__ __launch_bounds__(256) void k_out(
    const u16* __restrict__ aoh, const float* __restrict__ pair,
    const u16* __restrict__ Wt, const float* __restrict__ bo,
    const float* __restrict__ bg, float* __restrict__ out)
{
    const int t  = threadIdx.x;
    const int p0 = blockIdx.x * 64;
    const int w    = t >> 6;
    const int l15  = t & 15;
    const int quad = (t >> 4) & 3;
    const int p    = p0 + w * 16 + l15;

    // ---- B-frags: ao (bf16 direct) and pair (fp32 -> bf16 pack) ----
    bf16x8 aof[4], pf[4];
    #pragma unroll
    for (int kc = 0; kc < 4; ++kc) {
        aof[kc] = *(const bf16x8*)(aoh + ((size_t)kc * NP_ + p) * D_ + quad * 8);
        const float* pp = pair + (size_t)p * C_ + kc * 32 + quad * 8;
        pf[kc] = pack8(*(const float4*)pp, *(const float4*)(pp + 4));
    }

    const u16* WoT = Wt + 3 * 16384;
    const u16* WgT = Wt + 4 * 16384;

    #pragma unroll
    for (int nt = 0; nt < 8; ++nt) {
        f32x4 accO = {0.f, 0.f, 0.f, 0.f};
        f32x4 accG = {0.f, 0.f, 0.f, 0.f};
        #pragma unroll
        for (int kc = 0; kc < 4; ++kc) {
            bf16x8 awo = *(const bf16x8*)(WoT + (size_t)(nt * 16 + l15) * 128 + kc * 32 + quad * 8);
            bf16x8 awg = *(const bf16x8*)(WgT + (size_t)(nt * 16 + l15) * 128 + kc * 32 + quad * 8);
            accO = __builtin_amdgcn_mfma_f32_16x16x32_bf16(awo, aof[kc], accO, 0, 0, 0);
            accG = __builtin_amdgcn_mfma_f32_16x16x32_bf16(awg, pf[kc],  accG, 0, 0, 0);
        }
        const int ch = nt * 16 + quad * 4;
        float4 bo4 = *(const float4*)(bo + ch);
        float4 bg4 = *(const float4*)(bg + ch);
        float4 pr  = *(const float4*)(pair + (size_t)p * C_ + ch);
        float4 r;
        r.x = pr.x + (1.f / (1.f + __expf(-(accG[0] + bg4.x)))) * (accO[0] + bo4.x);
        r.y = pr.y + (1.f / (1.f + __expf(-(accG[1] + bg4.y)))) * (accO[1] + bo4.y);
        r.z = pr.z + (1.f / (1.f + __expf(-(accG[2] + bg4.z)))) * (accO[2] + bo4.z);
        r.w = pr.w + (1.f / (1.f + __expf(-(accG[3] + bg4.w)))) * (accO[3] + bo4.w);
        *(float4*)(out + (size_t)p * C_ + ch) = r;
    }
}

// ---------------------------------------------------------------------------
// Workspace (49.2 MB):
//   [0, 1 MB)    biasB fp32 [H][j][k]
//   [1, 17 MB)   qh bf16 [H][NP][32]  (Q in, O out in place)
//   [17, 33 MB)  kh bf16
//   [33, 49 MB)  vh bf16
//   [49 MB, +160K) Wt bf16 [5][128][128]  (WqT*s, WkT, WvT, WoT, WgT)
//   [.., +2K)    WbT fp32 [4][128]
// ---------------------------------------------------------------------------
extern "C" void kernel_launch(void* const* d_in, const int* in_sizes, int n_in,
                              void* d_out, int out_size, void* d_ws, size_t ws_size,
                              hipStream_t stream) {
    const float* pair  = (const float*)d_in[0];
    const float* ln_g  = (const float*)d_in[1];
    const float* ln_b  = (const float*)d_in[2];
    const float* Wq    = (const float*)d_in[3];
    const float* Wk    = (const float*)d_in[4];
    const float* Wv    = (const float*)d_in[5];
    const float* Wbias = (const float*)d_in[6];
    const float* Wo    = (const float*)d_in[7];
    const float* bo    = (const float*)d_in[8];
    const float* Wg    = (const float*)d_in[9];
    const float* bg    = (const float*)d_in[10];
    float* out = (float*)d_out;

    float* biasB = (float*)d_ws;
    u16* qh = (u16*)(biasB + (size_t)H_ * NP_);
    u16* kh = qh + (size_t)NP_ * C_;
    u16* vh = kh + (size_t)NP_ * C_;
    u16* Wt = vh + (size_t)NP_ * C_;
    float* WbT = (float*)(Wt + 5 * 16384);

    k_prep<<<81, 256, 0, stream>>>(Wq, Wk, Wv, Wo, Wg, Wbias, Wt, WbT);
    k_lnmm<<<NP_ / 32, 128, 0, stream>>>(pair, ln_g, ln_b, Wt, WbT, qh, kh, vh, biasB);
    k_attn<<<L_ * H_, 256, 0, stream>>>(qh, kh, vh, biasB);
    k_out<<<NP_ / 64, 256, 0, stream>>>(qh, pair, Wt, bo, bg, out);
}

// Round 8
// 248.243 us; speedup vs baseline: 4.3591x; 1.0433x over previous
//
#include <hip/hip_runtime.h>
#include <cstdint>
#include <cstddef>

#define L_ 256
#define C_ 128
#define H_ 4
#define D_ 32
#define NP_ (L_ * L_)

typedef unsigned short u16;
typedef uint32_t u32;
typedef __attribute__((ext_vector_type(8))) short bf16x8;   // 4 VGPRs: MFMA A/B frag
typedef __attribute__((ext_vector_type(4))) float f32x4;    // MFMA C/D frag

__device__ __forceinline__ float bflo(u32 u) { union { u32 i; float f; } v; v.i = u << 16; return v.f; }
__device__ __forceinline__ float bfhi(u32 u) { union { u32 i; float f; } v; v.i = u & 0xffff0000u; return v.f; }
__device__ __forceinline__ float b2f(u16 u) { union { u32 i; float f; } v; v.i = ((u32)u) << 16; return v.f; }
__device__ __forceinline__ u16 f2b(float f) {
    u32 x = __float_as_uint(f);
    return (u16)((x + 0x7fffu + ((x >> 16) & 1u)) >> 16);
}
__device__ __forceinline__ u32 pk2(float lo, float hi) {
    return ((u32)f2b(hi) << 16) | (u32)f2b(lo);
}
__device__ __forceinline__ bf16x8 pack8(float4 a, float4 b) {
    union { u32 u[4]; bf16x8 v; } r;
    r.u[0] = pk2(a.x, a.y); r.u[1] = pk2(a.z, a.w);
    r.u[2] = pk2(b.x, b.y); r.u[3] = pk2(b.z, b.w);
    return r.v;
}

// ---------------------------------------------------------------------------
// Kernel 0: weight prep, LDS-tiled transpose (coalesced both sides).
// Wt[mat][n][c] (bf16) = W_mat[c][n], mat = {Wq*1/sqrt(D), Wk, Wv, Wo, Wg}.
// WbT[h][c] (fp32) = Wbias[c][h].  grid = 21 x 256.
// ---------------------------------------------------------------------------
__global__ __launch_bounds__(256) void k_prep(
    const float* __restrict__ Wq, const float* __restrict__ Wk, const float* __restrict__ Wv,
    const float* __restrict__ Wo, const float* __restrict__ Wg,
    const float* __restrict__ Wbias, u16* __restrict__ Wt, float* __restrict__ WbT)
{
    __shared__ float tile[64][65];
    const int b = blockIdx.x, t = threadIdx.x;
    if (b < 20) {
        const int mat = b >> 2, tl = b & 3, tr = tl >> 1, tc = tl & 1;
        const float* W = (mat == 0) ? Wq : (mat == 1) ? Wk : (mat == 2) ? Wv : (mat == 3) ? Wo : Wg;
        const float s = (mat == 0) ? 0.17677669529663687f : 1.f;
        const int rlo = t >> 6, col = t & 63;
        #pragma unroll
        for (int m = 0; m < 16; ++m) {
            int row = m * 4 + rlo;
            tile[row][col] = W[(size_t)(tr * 64 + row) * C_ + tc * 64 + col];
        }
        __syncthreads();
        #pragma unroll
        for (int m = 0; m < 16; ++m) {
            int n = tc * 64 + m * 4 + rlo;
            int c = tr * 64 + col;
            Wt[mat * 16384 + n * C_ + c] = f2b(tile[col][m * 4 + rlo] * s);
        }
    } else {
        #pragma unroll
        for (int m = 0; m < 2; ++m) {
            int idx = m * 256 + t;
            int h = idx >> 7, c = idx & 127;
            WbT[h * C_ + c] = Wbias[c * H_ + h];
        }
    }
}

// ---------------------------------------------------------------------------
// Kernel 1: LayerNorm + Q/K/V projections + bias projection (bf16).
// Block = 128 thr (2 waves), 16 rows; grid = 4096 (32 waves/CU — 2x TLP).
// LN: 8 lanes/row. The 24 MFMA tiles split 12/12 across the 2 waves; wave 0
// also does the bias projection (64 tasks = 16 rows x 4 heads, one lane each).
// ---------------------------------------------------------------------------
__global__ __launch_bounds__(128) void k_lnmm(
    const float* __restrict__ pair, const float* __restrict__ ln_g, const float* __restrict__ ln_b,
    const u16* __restrict__ Wt, const float* __restrict__ WbT,
    u16* __restrict__ qh, u16* __restrict__ kh, u16* __restrict__ vh,
    u16* __restrict__ biasB)
{
    __shared__ u16 zsh[16][144];      // z rows bf16, stride 288 B

    const int t  = threadIdx.x;
    const int p0 = blockIdx.x * 16;
    const int row = t >> 3, seg = t & 7;

    // ---- LN: 8 lanes/row, interleaved float4 slots ----
    float4 xv[4];
    float sum = 0.f, ss = 0.f;
    #pragma unroll
    for (int i = 0; i < 4; ++i) {
        int c = (seg + 8 * i) * 4;
        float4 x = *(const float4*)(pair + (size_t)(p0 + row) * C_ + c);
        xv[i] = x;
        sum += x.x + x.y + x.z + x.w;
        ss  += x.x * x.x + x.y * x.y + x.z * x.z + x.w * x.w;
    }
    sum += __shfl_xor(sum, 1); sum += __shfl_xor(sum, 2); sum += __shfl_xor(sum, 4);
    ss  += __shfl_xor(ss, 1);  ss  += __shfl_xor(ss, 2);  ss  += __shfl_xor(ss, 4);
    float mu  = sum * (1.0f / C_);
    float var = ss * (1.0f / C_) - mu * mu;
    float rs  = rsqrtf(fmaxf(var, 0.f) + 1e-5f);

    #pragma unroll
    for (int i = 0; i < 4; ++i) {
        int c = (seg + 8 * i) * 4;
        float4 g4 = *(const float4*)(ln_g + c);
        float4 b4 = *(const float4*)(ln_b + c);
        float4 x  = xv[i];
        float z0 = (x.x - mu) * rs * g4.x + b4.x;
        float z1 = (x.y - mu) * rs * g4.y + b4.y;
        float z2 = (x.z - mu) * rs * g4.z + b4.z;
        float z3 = (x.w - mu) * rs * g4.w + b4.w;
        *(u32*)&zsh[row][c]     = pk2(z0, z1);
        *(u32*)&zsh[row][c + 2] = pk2(z2, z3);
    }
    __syncthreads();

    const int w    = t >> 6;
    const int l15  = t & 15;
    const int quad = (t >> 4) & 3;
    const int p    = p0 + l15;

    bf16x8 zf[4];
    #pragma unroll
    for (int kc = 0; kc < 4; ++kc)
        zf[kc] = *(const bf16x8*)&zsh[l15][kc * 32 + quad * 8];

    // ---- 12 MFMA tiles per wave (tt = w*12 + k; mat = tt>>3, mt = tt&7) ----
    #pragma unroll
    for (int k = 0; k < 12; ++k) {
        const int tt = w * 12 + k;
        const int mat = tt >> 3, mt = tt & 7;
        f32x4 acc = {0.f, 0.f, 0.f, 0.f};
        #pragma unroll
        for (int kc = 0; kc < 4; ++kc) {
            bf16x8 af = *(const bf16x8*)(Wt + (size_t)tt * 2048 + (size_t)l15 * 128 + kc * 32 + quad * 8);
            acc = __builtin_amdgcn_mfma_f32_16x16x32_bf16(af, zf[kc], acc, 0, 0, 0);
        }
        u16* dst = (mat == 0) ? qh : (mat == 1) ? kh : vh;
        const int hh = mt >> 1;
        const int cb = (mt & 1) * 16 + quad * 4;
        *(uint2*)(dst + ((size_t)hh * NP_ + p) * D_ + cb) =
            make_uint2(pk2(acc[0], acc[1]), pk2(acc[2], acc[3]));
    }

    // ---- bias projection on wave 0: lane t -> (row = t>>2, h = t&3), bf16 out ----
    if (w == 0) {
        const int br = t >> 2, h = t & 3;
        float a = 0.f;
        #pragma unroll
        for (int c8 = 0; c8 < C_; c8 += 8) {
            uint4 zz = *(const uint4*)&zsh[br][c8];
            float4 wb0 = *(const float4*)(WbT + h * C_ + c8);
            float4 wb1 = *(const float4*)(WbT + h * C_ + c8 + 4);
            a += bflo(zz.x) * wb0.x + bfhi(zz.x) * wb0.y
               + bflo(zz.y) * wb0.z + bfhi(zz.y) * wb0.w
               + bflo(zz.z) * wb1.x + bfhi(zz.z) * wb1.y
               + bflo(zz.w) * wb1.z + bfhi(zz.w) * wb1.w;
        }
        biasB[(size_t)h * NP_ + p0 + br] = f2b(a);
    }
}

// ---------------------------------------------------------------------------
// Kernel 2: attention, block per (i, h, half). 256 thr = 4 waves; wave w owns
// rows half*128 + w*32 .. +31 (2 j-tiles). grid = 2048 (j-split x2 for TLP).
// K and Q fragments read DIRECT from global (1 KB coalesced, L2-hot) — no Ksh.
// V transposed into LDS (stride 264: aligned b128 reads; one-time scatter).
// P round-trip through per-wave LDS, single-buffered (wave-internal order).
// kb software-prefetched one kc ahead. bias is bf16.
// ---------------------------------------------------------------------------
__global__ __launch_bounds__(256) void k_attn(
    u16* __restrict__ qh, const u16* __restrict__ kh, const u16* __restrict__ vh,
    const u16* __restrict__ biasB)
{
    __shared__ u16 Vsh[D_ * 264];      // V^T [d][k], stride 264 u16 (528 B)
    __shared__ u16 Psh[4][16][40];     // per-wave P buffer

    const int t = threadIdx.x;
    const int b = blockIdx.x;
    const int i    = b >> 3;
    const int h    = (b >> 1) & 3;
    const int half = b & 1;
    const int w    = t >> 6;
    const int l15  = t & 15;
    const int quad = (t >> 4) & 3;
    const int jbase = half * 128 + w * 32;

    const u16* Kg = kh + ((size_t)h * NP_ + i * L_) * D_;
    const u16* Vg = vh + ((size_t)h * NP_ + i * L_) * D_;
    u16*       Qg = qh + ((size_t)h * NP_ + i * L_) * D_;

    // ---- stage V transposed (coalesced read, scatter store; 4-way conflict OK) ----
    #pragma unroll
    for (int jj = 0; jj < 8; ++jj) {
        int idx = t + jj * 256;
        int r = idx >> 2, sg = idx & 3;
        union { uint4 q; u16 s[8]; } u;
        u.q = *(const uint4*)(Vg + r * D_ + sg * 8);
        #pragma unroll
        for (int m = 0; m < 8; ++m) Vsh[(sg * 8 + m) * 264 + r] = u.s[m];
    }

    // ---- Q A-frags direct from global ----
    bf16x8 qf[2];
    #pragma unroll
    for (int jt = 0; jt < 2; ++jt)
        qf[jt] = *(const bf16x8*)(Qg + (size_t)(jbase + jt * 16 + l15) * D_ + quad * 8);

    __syncthreads();

    const f32x4 z4 = {0.f, 0.f, 0.f, 0.f};
    f32x4 oacc[2][2];
    float psum[2][4];
    #pragma unroll
    for (int jt = 0; jt < 2; ++jt) {
        oacc[jt][0] = z4; oacc[jt][1] = z4;
        #pragma unroll
        for (int r = 0; r < 4; ++r) psum[jt][r] = 0.f;
    }

    const u16* bB = biasB + (size_t)h * NP_;

    // ---- K-frags: prefetch one kc ahead ----
    bf16x8 kb0 = *(const bf16x8*)(Kg + (size_t)l15 * D_ + quad * 8);
    bf16x8 kb1 = *(const bf16x8*)(Kg + (size_t)(16 + l15) * D_ + quad * 8);

    for (int kc = 0; kc < 8; ++kc) {
        bf16x8 nb0, nb1;
        if (kc < 7) {
            nb0 = *(const bf16x8*)(Kg + (size_t)((kc + 1) * 32 + l15) * D_ + quad * 8);
            nb1 = *(const bf16x8*)(Kg + (size_t)((kc + 1) * 32 + 16 + l15) * D_ + quad * 8);
        }
        bf16x8 vb0 = *(const bf16x8*)&Vsh[l15 * 264 + kc * 32 + quad * 8];
        bf16x8 vb1 = *(const bf16x8*)&Vsh[(16 + l15) * 264 + kc * 32 + quad * 8];

        #pragma unroll
        for (int jt = 0; jt < 2; ++jt) {
            f32x4 s0 = __builtin_amdgcn_mfma_f32_16x16x32_bf16(qf[jt], kb0, z4, 0, 0, 0);
            f32x4 s1 = __builtin_amdgcn_mfma_f32_16x16x32_bf16(qf[jt], kb1, z4, 0, 0, 0);

            const u16* bp = bB + (size_t)(jbase + jt * 16 + quad * 4) * L_ + kc * 32 + l15;
            u16 (*P)[40] = Psh[w];
            float e0[4], e1[4];
            #pragma unroll
            for (int r = 0; r < 4; ++r) {
                e0[r] = __expf(s0[r] + b2f(bp[r * L_]));
                e1[r] = __expf(s1[r] + b2f(bp[r * L_ + 16]));
                psum[jt][r] += e0[r] + e1[r];
            }
            #pragma unroll
            for (int r = 0; r < 4; ++r) {
                P[quad * 4 + r][l15]      = f2b(e0[r]);
                P[quad * 4 + r][16 + l15] = f2b(e1[r]);
            }
            bf16x8 pa = *(const bf16x8*)&P[l15][quad * 8];
            oacc[jt][0] = __builtin_amdgcn_mfma_f32_16x16x32_bf16(pa, vb0, oacc[jt][0], 0, 0, 0);
            oacc[jt][1] = __builtin_amdgcn_mfma_f32_16x16x32_bf16(pa, vb1, oacc[jt][1], 0, 0, 0);
        }
        kb0 = nb0; kb1 = nb1;
    }

    // ---- softmax denominators: reduce over the 16 lanes of each quad ----
    float rn[2][4];
    #pragma unroll
    for (int jt = 0; jt < 2; ++jt)
        #pragma unroll
        for (int r = 0; r < 4; ++r) {
            float s = psum[jt][r];
            s += __shfl_xor(s, 1); s += __shfl_xor(s, 2);
            s += __shfl_xor(s, 4); s += __shfl_xor(s, 8);
            rn[jt][r] = 1.f / s;
        }

    // ---- normalize + store O in place of Q ----
    #pragma unroll
    for (int jt = 0; jt < 2; ++jt) {
        #pragma unroll
        for (int r = 0; r < 4; ++r) {
            size_t rowo = (size_t)(jbase + jt * 16 + quad * 4 + r) * D_;
            Qg[rowo + l15]      = f2b(oacc[jt][0][r] * rn[jt][r]);
            Qg[rowo + 16 + l15] = f2b(oacc[jt][1][r] * rn[jt][r]);
        }
    }
}

// ---------------------------------------------------------------------------
// Kernel 3: out = pair + sigmoid(pair@Wg+bg) * (ao@Wo+bo). (unchanged r7)
// ---------------------------------------------------------------------------
__global__ __launch_bounds__(256) void k_out(
    const u16* __restrict__ aoh, const float* __restrict__ pair,
    const u16* __restrict__ Wt, const float* __restrict__ bo,
    const float* __restrict__ bg, float* __restrict__ out)
{
    const int t  = threadIdx.x;
    const int p0 = blockIdx.x * 64;
    const int w    = t >> 6;
    const int l15  = t & 15;
    const int quad = (t >> 4) & 3;
    const int p    = p0 + w * 16 + l15;

    bf16x8 aof[4], pf[4];
    #pragma unroll
    for (int kc = 0; kc < 4; ++kc) {
        aof[kc] = *(const bf16x8*)(aoh + ((size_t)kc * NP_ + p) * D_ + quad * 8);
        const float* pp = pair + (size_t)p * C_ + kc * 32 + quad * 8;
        pf[kc] = pack8(*(const float4*)pp, *(const float4*)(pp + 4));
    }

    const u16* WoT = Wt + 3 * 16384;
    const u16* WgT = Wt + 4 * 16384;

    #pragma unroll
    for (int nt = 0; nt < 8; ++nt) {
        f32x4 accO = {0.f, 0.f, 0.f, 0.f};
        f32x4 accG = {0.f, 0.f, 0.f, 0.f};
        #pragma unroll
        for (int kc = 0; kc < 4; ++kc) {
            bf16x8 awo = *(const bf16x8*)(WoT + (size_t)(nt * 16 + l15) * 128 + kc * 32 + quad * 8);
            bf16x8 awg = *(const bf16x8*)(WgT + (size_t)(nt * 16 + l15) * 128 + kc * 32 + quad * 8);
            accO = __builtin_amdgcn_mfma_f32_16x16x32_bf16(awo, aof[kc], accO, 0, 0, 0);
            accG = __builtin_amdgcn_mfma_f32_16x16x32_bf16(awg, pf[kc],  accG, 0, 0, 0);
        }
        const int ch = nt * 16 + quad * 4;
        float4 bo4 = *(const float4*)(bo + ch);
        float4 bg4 = *(const float4*)(bg + ch);
        float4 pr  = *(const float4*)(pair + (size_t)p * C_ + ch);
        float4 r;
        r.x = pr.x + (1.f / (1.f + __expf(-(accG[0] + bg4.x)))) * (accO[0] + bo4.x);
        r.y = pr.y + (1.f / (1.f + __expf(-(accG[1] + bg4.y)))) * (accO[1] + bo4.y);
        r.z = pr.z + (1.f / (1.f + __expf(-(accG[2] + bg4.z)))) * (accO[2] + bo4.z);
        r.w = pr.w + (1.f / (1.f + __expf(-(accG[3] + bg4.w)))) * (accO[3] + bo4.w);
        *(float4*)(out + (size_t)p * C_ + ch) = r;
    }
}

// ---------------------------------------------------------------------------
// Workspace (~51 MB):
//   [0, 0.5 MB)    biasB bf16 [H][j][k]
//   [+,  +16.8MB)  qh bf16 [H][NP][32]  (Q in, O out in place)
//   [+,  +16.8MB)  kh
//   [+,  +16.8MB)  vh
//   [+,  +160K)    Wt bf16 [5][128][128]
//   [+,  +2K)      WbT fp32 [4][128]
// ---------------------------------------------------------------------------
extern "C" void kernel_launch(void* const* d_in, const int* in_sizes, int n_in,
                              void* d_out, int out_size, void* d_ws, size_t ws_size,
                              hipStream_t stream) {
    const float* pair  = (const float*)d_in[0];
    const float* ln_g  = (const float*)d_in[1];
    const float* ln_b  = (const float*)d_in[2];
    const float* Wq    = (const float*)d_in[3];
    const float* Wk    = (const float*)d_in[4];
    const float* Wv    = (const float*)d_in[5];
    const float* Wbias = (const float*)d_in[6];
    const float* Wo    = (const float*)d_in[7];
    const float* bo    = (const float*)d_in[8];
    const float* Wg    = (const float*)d_in[9];
    const float* bg    = (const float*)d_in[10];
    float* out = (float*)d_out;

    u16* biasB = (u16*)d_ws;                          // 0.5 MB bf16
    u16* qh = biasB + (size_t)H_ * NP_;
    u16* kh = qh + (size_t)NP_ * C_;
    u16* vh = kh + (size_t)NP_ * C_;
    u16* Wt = vh + (size_t)NP_ * C_;
    float* WbT = (float*)(Wt + 5 * 16384);

    k_prep<<<21, 256, 0, stream>>>(Wq, Wk, Wv, Wo, Wg, Wbias, Wt, WbT);
    k_lnmm<<<NP_ / 16, 128, 0, stream>>>(pair, ln_g, ln_b, Wt, WbT, qh, kh, vh, biasB);
    k_attn<<<L_ * H_ * 2, 256, 0, stream>>>(qh, kh, vh, biasB);
    k_out<<<NP_ / 64, 256, 0, stream>>>(qh, pair, Wt, bo, bg, out);
}

// Round 9
// 214.008 us; speedup vs baseline: 5.0565x; 1.1600x over previous
//
#include <hip/hip_runtime.h>
#include <cstdint>
#include <cstddef>

#define L_ 256
#define C_ 128
#define H_ 4
#define D_ 32
#define NP_ (L_ * L_)

typedef unsigned short u16;
typedef uint32_t u32;
typedef __attribute__((ext_vector_type(8))) short bf16x8;   // 4 VGPRs: MFMA A/B frag
typedef __attribute__((ext_vector_type(4))) float f32x4;    // MFMA C/D frag

__device__ __forceinline__ float bflo(u32 u) { union { u32 i; float f; } v; v.i = u << 16; return v.f; }
__device__ __forceinline__ float bfhi(u32 u) { union { u32 i; float f; } v; v.i = u & 0xffff0000u; return v.f; }
__device__ __forceinline__ float b2f(u16 u) { union { u32 i; float f; } v; v.i = ((u32)u) << 16; return v.f; }
__device__ __forceinline__ u16 f2b(float f) {
    u32 x = __float_as_uint(f);
    return (u16)((x + 0x7fffu + ((x >> 16) & 1u)) >> 16);
}
__device__ __forceinline__ u32 pk2(float lo, float hi) {
    return ((u32)f2b(hi) << 16) | (u32)f2b(lo);
}
__device__ __forceinline__ bf16x8 pack8(float4 a, float4 b) {
    union { u32 u[4]; bf16x8 v; } r;
    r.u[0] = pk2(a.x, a.y); r.u[1] = pk2(a.z, a.w);
    r.u[2] = pk2(b.x, b.y); r.u[3] = pk2(b.z, b.w);
    return r.v;
}

// ---------------------------------------------------------------------------
// Kernel 0: weight prep, LDS-tiled transpose (coalesced both sides).
// Wt[mat][n][c] (bf16) = W_mat[c][n], mat = {Wq*1/sqrt(D), Wk, Wv, Wo, Wg}.
// WbT[h][c] (fp32) = Wbias[c][h].  grid = 21 x 256.
// ---------------------------------------------------------------------------
__global__ __launch_bounds__(256) void k_prep(
    const float* __restrict__ Wq, const float* __restrict__ Wk, const float* __restrict__ Wv,
    const float* __restrict__ Wo, const float* __restrict__ Wg,
    const float* __restrict__ Wbias, u16* __restrict__ Wt, float* __restrict__ WbT)
{
    __shared__ float tile[64][65];
    const int b = blockIdx.x, t = threadIdx.x;
    if (b < 20) {
        const int mat = b >> 2, tl = b & 3, tr = tl >> 1, tc = tl & 1;
        const float* W = (mat == 0) ? Wq : (mat == 1) ? Wk : (mat == 2) ? Wv : (mat == 3) ? Wo : Wg;
        const float s = (mat == 0) ? 0.17677669529663687f : 1.f;
        const int rlo = t >> 6, col = t & 63;
        #pragma unroll
        for (int m = 0; m < 16; ++m) {
            int row = m * 4 + rlo;
            tile[row][col] = W[(size_t)(tr * 64 + row) * C_ + tc * 64 + col];
        }
        __syncthreads();
        #pragma unroll
        for (int m = 0; m < 16; ++m) {
            int n = tc * 64 + m * 4 + rlo;
            int c = tr * 64 + col;
            Wt[mat * 16384 + n * C_ + c] = f2b(tile[col][m * 4 + rlo] * s);
        }
    } else {
        #pragma unroll
        for (int m = 0; m < 2; ++m) {
            int idx = m * 256 + t;
            int h = idx >> 7, c = idx & 127;
            WbT[h * C_ + c] = Wbias[c * H_ + h];
        }
    }
}

// ---------------------------------------------------------------------------
// Kernel 1: LayerNorm + Q/K/V projections + bias projection.
// Block = 256 thr (4 waves), 64 rows; grid = 1024. ILP design: each wave holds
// B-frags for all 4 j-tiles (zf[4][4]) and computes 6 (mat,mt) tiles; every
// Wt A-frag load feeds 4 MFMAs (was 1). 6-tile loop unrolled -> the compiler
// can pipeline next-tile loads under current-tile MFMAs.
// biasT output TRANSPOSED bf16 [h][k][j] for k_attn's vector loads.
// ---------------------------------------------------------------------------
__global__ __launch_bounds__(256) void k_lnmm(
    const float* __restrict__ pair, const float* __restrict__ ln_g, const float* __restrict__ ln_b,
    const u16* __restrict__ Wt, const float* __restrict__ WbT,
    u16* __restrict__ qh, u16* __restrict__ kh, u16* __restrict__ vh,
    u16* __restrict__ biasT)
{
    __shared__ u16 zsh[64][136];      // z rows bf16, stride 272 B

    const int t  = threadIdx.x;
    const int p0 = blockIdx.x * 64;
    const int row = t >> 2, seg = t & 3;

    // ---- LN: 4 lanes/row, interleaved float4 slots (coalesced) ----
    float4 xv[8];
    float sum = 0.f, ss = 0.f;
    #pragma unroll
    for (int i = 0; i < 8; ++i) {
        int c = (seg + 4 * i) * 4;
        float4 x = *(const float4*)(pair + (size_t)(p0 + row) * C_ + c);
        xv[i] = x;
        sum += x.x + x.y + x.z + x.w;
        ss  += x.x * x.x + x.y * x.y + x.z * x.z + x.w * x.w;
    }
    sum += __shfl_xor(sum, 1); sum += __shfl_xor(sum, 2);
    ss  += __shfl_xor(ss, 1);  ss  += __shfl_xor(ss, 2);
    float mu  = sum * (1.0f / C_);
    float var = ss * (1.0f / C_) - mu * mu;
    float rs  = rsqrtf(fmaxf(var, 0.f) + 1e-5f);

    #pragma unroll
    for (int i = 0; i < 8; ++i) {
        int c = (seg + 4 * i) * 4;
        float4 g4 = *(const float4*)(ln_g + c);
        float4 b4 = *(const float4*)(ln_b + c);
        float4 x  = xv[i];
        float z0 = (x.x - mu) * rs * g4.x + b4.x;
        float z1 = (x.y - mu) * rs * g4.y + b4.y;
        float z2 = (x.z - mu) * rs * g4.z + b4.z;
        float z3 = (x.w - mu) * rs * g4.w + b4.w;
        *(u32*)&zsh[row][c]     = pk2(z0, z1);
        *(u32*)&zsh[row][c + 2] = pk2(z2, z3);
    }
    __syncthreads();

    const int w    = t >> 6;
    const int l15  = t & 15;
    const int quad = (t >> 4) & 3;

    // ---- B-frags for ALL 4 j-tiles (loaded once: 16 b128 reads) ----
    bf16x8 zf[4][4];
    #pragma unroll
    for (int jt = 0; jt < 4; ++jt)
        #pragma unroll
        for (int kc = 0; kc < 4; ++kc)
            zf[jt][kc] = *(const bf16x8*)&zsh[jt * 16 + l15][kc * 32 + quad * 8];

    // ---- 6 (mat,mt) tiles per wave; each A-frag feeds 4 MFMAs ----
    #pragma unroll
    for (int k = 0; k < 6; ++k) {
        const int tt = w * 6 + k;
        const int mat = tt >> 3, mt = tt & 7;
        f32x4 acc0 = {0.f,0.f,0.f,0.f}, acc1 = acc0, acc2 = acc0, acc3 = acc0;
        #pragma unroll
        for (int kc = 0; kc < 4; ++kc) {
            bf16x8 af = *(const bf16x8*)(Wt + (size_t)tt * 2048 + (size_t)l15 * 128 + kc * 32 + quad * 8);
            acc0 = __builtin_amdgcn_mfma_f32_16x16x32_bf16(af, zf[0][kc], acc0, 0, 0, 0);
            acc1 = __builtin_amdgcn_mfma_f32_16x16x32_bf16(af, zf[1][kc], acc1, 0, 0, 0);
            acc2 = __builtin_amdgcn_mfma_f32_16x16x32_bf16(af, zf[2][kc], acc2, 0, 0, 0);
            acc3 = __builtin_amdgcn_mfma_f32_16x16x32_bf16(af, zf[3][kc], acc3, 0, 0, 0);
        }
        u16* dst = (mat == 0) ? qh : (mat == 1) ? kh : vh;
        const int hh = mt >> 1;
        const int cb = (mt & 1) * 16 + quad * 4;
        f32x4 accs[4] = {acc0, acc1, acc2, acc3};
        #pragma unroll
        for (int jt = 0; jt < 4; ++jt) {
            const int p = p0 + jt * 16 + l15;
            *(uint2*)(dst + ((size_t)hh * NP_ + p) * D_ + cb) =
                make_uint2(pk2(accs[jt][0], accs[jt][1]), pk2(accs[jt][2], accs[jt][3]));
        }
    }

    // ---- bias projection: thread (row, h=seg); biasT[h][k][j] bf16 ----
    {
        float a = 0.f;
        #pragma unroll
        for (int c8 = 0; c8 < C_; c8 += 8) {
            uint4 zz = *(const uint4*)&zsh[row][c8];
            float4 wb0 = *(const float4*)(WbT + seg * C_ + c8);
            float4 wb1 = *(const float4*)(WbT + seg * C_ + c8 + 4);
            a += bflo(zz.x) * wb0.x + bfhi(zz.x) * wb0.y
               + bflo(zz.y) * wb0.z + bfhi(zz.y) * wb0.w
               + bflo(zz.z) * wb1.x + bfhi(zz.z) * wb1.y
               + bflo(zz.w) * wb1.z + bfhi(zz.w) * wb1.w;
        }
        const int p = p0 + row;                       // p = j*256 + k
        biasT[(size_t)seg * NP_ + (p & 255) * 256 + (p >> 8)] = f2b(a);
    }
}

// ---------------------------------------------------------------------------
// Kernel 2: attention, block per (i,h); 256 thr = 4 waves; wave w owns rows
// w*64..+63 (4 j-tiles -> 4-way interleave of the S->exp->P->PV chain).
// K/Q frags direct from global (L2-hot); each K-frag pair feeds 8 S-MFMAs.
// Bias from transposed biasT[h][k][j]: 2 coalesced uint2 loads per (jt,kc).
// grid = 1024.
// ---------------------------------------------------------------------------
__global__ __launch_bounds__(256) void k_attn(
    u16* __restrict__ qh, const u16* __restrict__ kh, const u16* __restrict__ vh,
    const u16* __restrict__ biasT)
{
    __shared__ u16 Vsh[D_ * 264];      // V^T [d][k], stride 264 u16
    __shared__ u16 Psh[4][16][40];     // per-wave P buffer

    const int t = threadIdx.x;
    const int i = blockIdx.x >> 2;
    const int h = blockIdx.x & 3;
    const int w    = t >> 6;
    const int l15  = t & 15;
    const int quad = (t >> 4) & 3;
    const int jbase = w * 64;

    const u16* Kg = kh + ((size_t)h * NP_ + i * L_) * D_;
    const u16* Vg = vh + ((size_t)h * NP_ + i * L_) * D_;
    u16*       Qg = qh + ((size_t)h * NP_ + i * L_) * D_;

    // ---- stage V transposed ----
    #pragma unroll
    for (int jj = 0; jj < 8; ++jj) {
        int idx = t + jj * 256;
        int r = idx >> 2, sg = idx & 3;
        union { uint4 q; u16 s[8]; } u;
        u.q = *(const uint4*)(Vg + r * D_ + sg * 8);
        #pragma unroll
        for (int m = 0; m < 8; ++m) Vsh[(sg * 8 + m) * 264 + r] = u.s[m];
    }

    // ---- Q A-frags ----
    bf16x8 qf[4];
    #pragma unroll
    for (int jt = 0; jt < 4; ++jt)
        qf[jt] = *(const bf16x8*)(Qg + (size_t)(jbase + jt * 16 + l15) * D_ + quad * 8);

    __syncthreads();

    const f32x4 z4 = {0.f, 0.f, 0.f, 0.f};
    f32x4 oacc[4][2];
    float psum[4][4];
    #pragma unroll
    for (int jt = 0; jt < 4; ++jt) {
        oacc[jt][0] = z4; oacc[jt][1] = z4;
        #pragma unroll
        for (int r = 0; r < 4; ++r) psum[jt][r] = 0.f;
    }

    const u16* bT = biasT + (size_t)h * NP_;   // [k][j]

    bf16x8 kb0 = *(const bf16x8*)(Kg + (size_t)l15 * D_ + quad * 8);
    bf16x8 kb1 = *(const bf16x8*)(Kg + (size_t)(16 + l15) * D_ + quad * 8);

    for (int kc = 0; kc < 8; ++kc) {
        bf16x8 nb0, nb1;
        if (kc < 7) {
            nb0 = *(const bf16x8*)(Kg + (size_t)((kc + 1) * 32 + l15) * D_ + quad * 8);
            nb1 = *(const bf16x8*)(Kg + (size_t)((kc + 1) * 32 + 16 + l15) * D_ + quad * 8);
        }
        bf16x8 vb0 = *(const bf16x8*)&Vsh[l15 * 264 + kc * 32 + quad * 8];
        bf16x8 vb1 = *(const bf16x8*)&Vsh[(16 + l15) * 264 + kc * 32 + quad * 8];

        #pragma unroll
        for (int jt = 0; jt < 4; ++jt) {
            f32x4 s0 = __builtin_amdgcn_mfma_f32_16x16x32_bf16(qf[jt], kb0, z4, 0, 0, 0);
            f32x4 s1 = __builtin_amdgcn_mfma_f32_16x16x32_bf16(qf[jt], kb1, z4, 0, 0, 0);

            // bias: rows j..j+3 for col kc*32+l15 (tile0) and +16 (tile1)
            const int j0 = jbase + jt * 16 + quad * 4;
            uint2 bv0 = *(const uint2*)(bT + (size_t)(kc * 32 + l15) * L_ + j0);
            uint2 bv1 = *(const uint2*)(bT + (size_t)(kc * 32 + 16 + l15) * L_ + j0);
            const u16* b0p = (const u16*)&bv0;
            const u16* b1p = (const u16*)&bv1;

            u16 (*P)[40] = Psh[w];
            float e0[4], e1[4];
            #pragma unroll
            for (int r = 0; r < 4; ++r) {
                e0[r] = __expf(s0[r] + b2f(b0p[r]));
                e1[r] = __expf(s1[r] + b2f(b1p[r]));
                psum[jt][r] += e0[r] + e1[r];
            }
            #pragma unroll
            for (int r = 0; r < 4; ++r) {
                P[quad * 4 + r][l15]      = f2b(e0[r]);
                P[quad * 4 + r][16 + l15] = f2b(e1[r]);
            }
            bf16x8 pa = *(const bf16x8*)&P[l15][quad * 8];
            oacc[jt][0] = __builtin_amdgcn_mfma_f32_16x16x32_bf16(pa, vb0, oacc[jt][0], 0, 0, 0);
            oacc[jt][1] = __builtin_amdgcn_mfma_f32_16x16x32_bf16(pa, vb1, oacc[jt][1], 0, 0, 0);
        }
        kb0 = nb0; kb1 = nb1;
    }

    // ---- softmax denominators ----
    float rn[4][4];
    #pragma unroll
    for (int jt = 0; jt < 4; ++jt)
        #pragma unroll
        for (int r = 0; r < 4; ++r) {
            float s = psum[jt][r];
            s += __shfl_xor(s, 1); s += __shfl_xor(s, 2);
            s += __shfl_xor(s, 4); s += __shfl_xor(s, 8);
            rn[jt][r] = 1.f / s;
        }

    // ---- normalize + store O in place of Q ----
    #pragma unroll
    for (int jt = 0; jt < 4; ++jt) {
        #pragma unroll
        for (int r = 0; r < 4; ++r) {
            size_t rowo = (size_t)(jbase + jt * 16 + quad * 4 + r) * D_;
            Qg[rowo + l15]      = f2b(oacc[jt][0][r] * rn[jt][r]);
            Qg[rowo + 16 + l15] = f2b(oacc[jt][1][r] * rn[jt][r]);
        }
    }
}

// ---------------------------------------------------------------------------
// Kernel 3: out = pair + sigmoid(pair@Wg+bg) * (ao@Wo+bo). ILP: wave owns
// 2 row-groups (32 rows); each W A-frag feeds 2 MFMAs. Block = 256 thr,
// 128 rows; grid = 512.
// ---------------------------------------------------------------------------
__global__ __launch_bounds__(256) void k_out(
    const u16* __restrict__ aoh, const float* __restrict__ pair,
    const u16* __restrict__ Wt, const float* __restrict__ bo,
    const float* __restrict__ bg, float* __restrict__ out)
{
    const int t  = threadIdx.x;
    const int p0 = blockIdx.x * 128;
    const int w    = t >> 6;
    const int l15  = t & 15;
    const int quad = (t >> 4) & 3;

    // ---- B-frags: 2 row-groups of ao (bf16) and pair (fp32->bf16) ----
    bf16x8 aof[2][4], pf[2][4];
    int prow[2];
    #pragma unroll
    for (int g = 0; g < 2; ++g) {
        prow[g] = p0 + w * 32 + g * 16 + l15;
        #pragma unroll
        for (int kc = 0; kc < 4; ++kc) {
            aof[g][kc] = *(const bf16x8*)(aoh + ((size_t)kc * NP_ + prow[g]) * D_ + quad * 8);
            const float* pp = pair + (size_t)prow[g] * C_ + kc * 32 + quad * 8;
            pf[g][kc] = pack8(*(const float4*)pp, *(const float4*)(pp + 4));
        }
    }

    const u16* WoT = Wt + 3 * 16384;
    const u16* WgT = Wt + 4 * 16384;

    #pragma unroll
    for (int nt = 0; nt < 8; ++nt) {
        f32x4 accO0 = {0.f,0.f,0.f,0.f}, accO1 = accO0, accG0 = accO0, accG1 = accO0;
        #pragma unroll
        for (int kc = 0; kc < 4; ++kc) {
            bf16x8 awo = *(const bf16x8*)(WoT + (size_t)(nt * 16 + l15) * 128 + kc * 32 + quad * 8);
            bf16x8 awg = *(const bf16x8*)(WgT + (size_t)(nt * 16 + l15) * 128 + kc * 32 + quad * 8);
            accO0 = __builtin_amdgcn_mfma_f32_16x16x32_bf16(awo, aof[0][kc], accO0, 0, 0, 0);
            accO1 = __builtin_amdgcn_mfma_f32_16x16x32_bf16(awo, aof[1][kc], accO1, 0, 0, 0);
            accG0 = __builtin_amdgcn_mfma_f32_16x16x32_bf16(awg, pf[0][kc],  accG0, 0, 0, 0);
            accG1 = __builtin_amdgcn_mfma_f32_16x16x32_bf16(awg, pf[1][kc],  accG1, 0, 0, 0);
        }
        const int ch = nt * 16 + quad * 4;
        float4 bo4 = *(const float4*)(bo + ch);
        float4 bg4 = *(const float4*)(bg + ch);
        f32x4 aO[2] = {accO0, accO1}, aG[2] = {accG0, accG1};
        #pragma unroll
        for (int g = 0; g < 2; ++g) {
            float4 pr = *(const float4*)(pair + (size_t)prow[g] * C_ + ch);
            float4 r;
            r.x = pr.x + (1.f / (1.f + __expf(-(aG[g][0] + bg4.x)))) * (aO[g][0] + bo4.x);
            r.y = pr.y + (1.f / (1.f + __expf(-(aG[g][1] + bg4.y)))) * (aO[g][1] + bo4.y);
            r.z = pr.z + (1.f / (1.f + __expf(-(aG[g][2] + bg4.z)))) * (aO[g][2] + bo4.z);
            r.w = pr.w + (1.f / (1.f + __expf(-(aG[g][3] + bg4.w)))) * (aO[g][3] + bo4.w);
            *(float4*)(out + (size_t)prow[g] * C_ + ch) = r;
        }
    }
}

// ---------------------------------------------------------------------------
// Workspace (~51 MB):
//   [0, 0.5 MB)    biasT bf16 [H][k][j]   (transposed)
//   [+,  +16.8MB)  qh bf16 [H][NP][32]    (Q in, O out in place)
//   [+,  +16.8MB)  kh
//   [+,  +16.8MB)  vh
//   [+,  +160K)    Wt bf16 [5][128][128]
//   [+,  +2K)      WbT fp32 [4][128]
// ---------------------------------------------------------------------------
extern "C" void kernel_launch(void* const* d_in, const int* in_sizes, int n_in,
                              void* d_out, int out_size, void* d_ws, size_t ws_size,
                              hipStream_t stream) {
    const float* pair  = (const float*)d_in[0];
    const float* ln_g  = (const float*)d_in[1];
    const float* ln_b  = (const float*)d_in[2];
    const float* Wq    = (const float*)d_in[3];
    const float* Wk    = (const float*)d_in[4];
    const float* Wv    = (const float*)d_in[5];
    const float* Wbias = (const float*)d_in[6];
    const float* Wo    = (const float*)d_in[7];
    const float* bo    = (const float*)d_in[8];
    const float* Wg    = (const float*)d_in[9];
    const float* bg    = (const float*)d_in[10];
    float* out = (float*)d_out;

    u16* biasT = (u16*)d_ws;                          // 0.5 MB bf16
    u16* qh = biasT + (size_t)H_ * NP_;
    u16* kh = qh + (size_t)NP_ * C_;
    u16* vh = kh + (size_t)NP_ * C_;
    u16* Wt = vh + (size_t)NP_ * C_;
    float* WbT = (float*)(Wt + 5 * 16384);

    k_prep<<<21, 256, 0, stream>>>(Wq, Wk, Wv, Wo, Wg, Wbias, Wt, WbT);
    k_lnmm<<<NP_ / 64, 256, 0, stream>>>(pair, ln_g, ln_b, Wt, WbT, qh, kh, vh, biasT);
    k_attn<<<L_ * H_, 256, 0, stream>>>(qh, kh, vh, biasT);
    k_out<<<NP_ / 128, 256, 0, stream>>>(qh, pair, Wt, bo, bg, out);
}